// Round 3
// baseline (483.186 us; speedup 1.0000x reference)
//
#include <hip/hip_runtime.h>
#include <math.h>

// Problem constants (from reference): V=3, B=2, C=64, NS=32, H=128, W=128
constexpr int NV = 3;
constexpr int NB = 2;
constexpr int NC = 64;
constexpr int NSC = 32;
constexpr int NH = 128;
constexpr int NW = 128;

// ---------------------------------------------------------------------------
// 4x4 inverse (adjugate, double precision) — mirrors jnp.linalg.inv fidelity
// ---------------------------------------------------------------------------
__device__ void inv4x4(const double* m, double* out) {
    double inv[16];
    inv[0]  =  m[5]*m[10]*m[15] - m[5]*m[11]*m[14] - m[9]*m[6]*m[15] + m[9]*m[7]*m[14] + m[13]*m[6]*m[11] - m[13]*m[7]*m[10];
    inv[4]  = -m[4]*m[10]*m[15] + m[4]*m[11]*m[14] + m[8]*m[6]*m[15] - m[8]*m[7]*m[14] - m[12]*m[6]*m[11] + m[12]*m[7]*m[10];
    inv[8]  =  m[4]*m[9]*m[15]  - m[4]*m[11]*m[13] - m[8]*m[5]*m[15] + m[8]*m[7]*m[13] + m[12]*m[5]*m[11] - m[12]*m[7]*m[9];
    inv[12] = -m[4]*m[9]*m[14]  + m[4]*m[10]*m[13] + m[8]*m[5]*m[14] - m[8]*m[6]*m[13] - m[12]*m[5]*m[10] + m[12]*m[6]*m[9];
    inv[1]  = -m[1]*m[10]*m[15] + m[1]*m[11]*m[14] + m[9]*m[2]*m[15] - m[9]*m[3]*m[14] - m[13]*m[2]*m[11] + m[13]*m[3]*m[10];
    inv[5]  =  m[0]*m[10]*m[15] - m[0]*m[11]*m[14] - m[8]*m[2]*m[15] + m[8]*m[3]*m[14] + m[12]*m[2]*m[11] - m[12]*m[3]*m[10];
    inv[9]  = -m[0]*m[9]*m[15]  + m[0]*m[11]*m[13] + m[8]*m[1]*m[15] - m[8]*m[3]*m[13] - m[12]*m[1]*m[11] + m[12]*m[3]*m[9];
    inv[13] =  m[0]*m[9]*m[14]  - m[0]*m[10]*m[13] - m[8]*m[1]*m[14] + m[8]*m[2]*m[13] + m[12]*m[1]*m[10] - m[12]*m[2]*m[9];
    inv[2]  =  m[1]*m[6]*m[15]  - m[1]*m[7]*m[14]  - m[5]*m[2]*m[15] + m[5]*m[3]*m[14] + m[13]*m[2]*m[7]  - m[13]*m[3]*m[6];
    inv[6]  = -m[0]*m[6]*m[15]  + m[0]*m[7]*m[14]  + m[4]*m[2]*m[15] - m[4]*m[3]*m[14] - m[12]*m[2]*m[7]  + m[12]*m[3]*m[6];
    inv[10] =  m[0]*m[5]*m[15]  - m[0]*m[7]*m[13]  - m[4]*m[1]*m[15] + m[4]*m[3]*m[13] + m[12]*m[1]*m[7]  - m[12]*m[3]*m[5];
    inv[14] = -m[0]*m[5]*m[14]  + m[0]*m[6]*m[13]  + m[4]*m[1]*m[14] - m[4]*m[2]*m[13] - m[12]*m[1]*m[6]  + m[12]*m[2]*m[5];
    inv[3]  = -m[1]*m[6]*m[11]  + m[1]*m[7]*m[10]  + m[5]*m[2]*m[11] - m[5]*m[3]*m[10] - m[9]*m[2]*m[7]   + m[9]*m[3]*m[6];
    inv[7]  =  m[0]*m[6]*m[11]  - m[0]*m[7]*m[10]  - m[4]*m[2]*m[11] + m[4]*m[3]*m[10] + m[8]*m[2]*m[7]   - m[8]*m[3]*m[6];
    inv[11] = -m[0]*m[5]*m[11]  + m[0]*m[7]*m[9]   + m[4]*m[1]*m[11] - m[4]*m[3]*m[9]  - m[8]*m[1]*m[7]   + m[8]*m[3]*m[5];
    inv[15] =  m[0]*m[5]*m[10]  - m[0]*m[6]*m[9]   - m[4]*m[1]*m[10] + m[4]*m[2]*m[9]  + m[8]*m[1]*m[6]   - m[8]*m[2]*m[5];
    double det = m[0]*inv[0] + m[1]*inv[4] + m[2]*inv[8] + m[3]*inv[12];
    det = 1.0 / det;
    for (int i = 0; i < 16; ++i) out[i] = inv[i] * det;
}

__device__ void mat4mul(const double* a, const double* b, double* o) {
    for (int i = 0; i < 4; ++i)
        for (int j = 0; j < 4; ++j) {
            double s = 0.0;
            for (int k = 0; k < 4; ++k) s += a[i*4+k] * b[k*4+j];
            o[i*4+j] = s;
        }
}

// ---------------------------------------------------------------------------
// Setup: per (src view, batch) compute rot(3x3)+trans(3) of the homography
// proj = src_P @ src_w2c @ inv(ref_P @ ref_w2c)
// rt layout: (2, B, 12) = rot row-major [0..8], trans [9..11]
// ---------------------------------------------------------------------------
__global__ void setup_kernel(const float* __restrict__ intr,
                             const float* __restrict__ c2w,
                             float* __restrict__ rt) {
    int t = threadIdx.x;
    if (t >= 2 * NB) return;
    int vi = t >> 1;         // 0 -> view 1, 1 -> view 2
    int b  = t & 1;
    int v  = vi + 1;

    double src_c2w[16], ref_c2w[16];
    for (int i = 0; i < 16; ++i) {
        src_c2w[i] = (double)c2w[(v * NB + b) * 16 + i];
        ref_c2w[i] = (double)c2w[(0 * NB + b) * 16 + i];
    }
    double src_w2c[16], ref_w2c[16];
    inv4x4(src_c2w, src_w2c);
    inv4x4(ref_c2w, ref_w2c);

    double srcP[16], refP[16];
    for (int i = 0; i < 16; ++i) { srcP[i] = src_w2c[i]; refP[i] = ref_w2c[i]; }
    for (int r = 0; r < 3; ++r)
        for (int c = 0; c < 3; ++c) {
            srcP[r*4+c] = (double)intr[(v * NB + b) * 9 + r*3 + c];
            refP[r*4+c] = (double)intr[(0 * NB + b) * 9 + r*3 + c];
        }

    double M1[16], M2[16], M2inv[16];
    mat4mul(srcP, src_w2c, M1);
    mat4mul(refP, ref_w2c, M2);
    inv4x4(M2, M2inv);
    double proj[16];
    mat4mul(M1, M2inv, proj);

    float* o = rt + (vi * NB + b) * 12;
    o[0] = (float)proj[0];  o[1] = (float)proj[1];  o[2]  = (float)proj[2];
    o[3] = (float)proj[4];  o[4] = (float)proj[5];  o[5]  = (float)proj[6];
    o[6] = (float)proj[8];  o[7] = (float)proj[9];  o[8]  = (float)proj[10];
    o[9] = (float)proj[3];  o[10] = (float)proj[7]; o[11] = (float)proj[11];
}

// ---------------------------------------------------------------------------
// Transpose features (V*B, C, H, W) -> (V*B, H, W, C) so the 64 channels at a
// (y,x) tap are contiguous. One block per (vb, y) row. +1 pad kills conflicts.
// ---------------------------------------------------------------------------
__global__ __launch_bounds__(256) void transpose_kernel(const float* __restrict__ in,
                                                        float* __restrict__ out) {
    __shared__ float tile[NC][NW + 1];
    const int y  = blockIdx.x;
    const int vb = blockIdx.y;

    for (int i = threadIdx.x; i < NC * NW; i += 256) {
        int c = i >> 7;          // /128
        int x = i & (NW - 1);
        tile[c][x] = in[((size_t)(vb * NC + c) * NH + y) * NW + x];
    }
    __syncthreads();
    float* dst = out + ((size_t)vb * NH + y) * NW * NC;
    for (int i = threadIdx.x; i < NC * NW; i += 256) {
        int x = i >> 6;          // /64
        int c = i & (NC - 1);
        dst[x * NC + c] = tile[c][x];
    }
}

// ---------------------------------------------------------------------------
// Main cost kernel v3: lane = pixel. Block 256 = 2 rows of 128 px.
// Grid: (H/2, NS, B). Each lane owns one pixel: computes its own geometry,
// then loops over 16 float4 channel-chunks accumulating squared residuals
// IN-LANE (no per-pixel shuffles). 9 independent float4 loads per chunk give
// deep MLP; single 6-shuffle wave reduce + atomicAdd at the end.
// ---------------------------------------------------------------------------
__global__ __launch_bounds__(256) void cost_kernel(
    const float* __restrict__ ft,     // (V, B, H, W, C) transposed features
    const float* __restrict__ depth,  // (B, H, W)
    const float* __restrict__ scale,  // (B, NS)
    const float* __restrict__ rt,     // (2, B, 12)
    float* __restrict__ cost)         // (B, NS) -- pre-zeroed
{
    const int tid = threadIdx.x;
    const int ns  = blockIdx.y;
    const int b   = blockIdx.z;
    const int x   = tid & (NW - 1);
    const int y   = blockIdx.x * 2 + (tid >> 7);

    const float s = scale[b * NSC + ns];
    const float d = depth[(b * NH + y) * NW + x] * s;

    const float4* f0  = (const float4*)(ft + (((size_t)(0 * NB + b) * NH + y) * NW + x) * NC);
    const float4* fv1 = (const float4*)(ft + ((size_t)(1 * NB + b) * NH) * NW * NC);
    const float4* fv2 = (const float4*)(ft + ((size_t)(2 * NB + b) * NH) * NW * NC);

    // ix = sx * (64/63.5) - 0.5 (algebraic fold of the grid normalize chain)
    const float CXY = 64.0f / 63.5f;
    const float fx = (float)x;
    const float fy = (float)y;

    // per-view geometry -> 4 tap indices (float4 units) + 4 weights
    int   ti[2][4];
    float tw[2][4];
#pragma unroll
    for (int vi = 0; vi < 2; ++vi) {
        float R[12];
#pragma unroll
        for (int k = 0; k < 12; ++k) R[k] = rt[(vi * NB + b) * 12 + k];
        float px = (R[0] * fx + R[1] * fy + R[2]) * d + R[9];
        float py = (R[3] * fx + R[4] * fy + R[5]) * d + R[10];
        float pz = (R[6] * fx + R[7] * fy + R[8]) * d + R[11];
        float invz = __builtin_amdgcn_rcpf(pz);
        float ix = (px * invz) * CXY - 0.5f;
        float iy = (py * invz) * CXY - 0.5f;

        float x0f = floorf(ix), y0f = floorf(iy);
        float wx1 = ix - x0f, wx0 = 1.f - wx1;
        float wy1 = iy - y0f, wy0 = 1.f - wy1;

        float mx0 = (x0f >= 0.f  && x0f <= 127.f) ? wx0 : 0.f;
        float mx1 = (x0f >= -1.f && x0f <= 126.f) ? wx1 : 0.f;
        float my0 = (y0f >= 0.f  && y0f <= 127.f) ? wy0 : 0.f;
        float my1 = (y0f >= -1.f && y0f <= 126.f) ? wy1 : 0.f;

        int xi0 = (int)fminf(fmaxf(x0f, 0.f), 127.f);
        int yi0 = (int)fminf(fmaxf(y0f, 0.f), 127.f);
        int xi1 = (int)fminf(fmaxf(x0f + 1.f, 0.f), 127.f);
        int yi1 = (int)fminf(fmaxf(y0f + 1.f, 0.f), 127.f);

        ti[vi][0] = (yi0 * NW + xi0) * (NC / 4);
        ti[vi][1] = (yi0 * NW + xi1) * (NC / 4);
        ti[vi][2] = (yi1 * NW + xi0) * (NC / 4);
        ti[vi][3] = (yi1 * NW + xi1) * (NC / 4);
        tw[vi][0] = mx0 * my0;
        tw[vi][1] = mx1 * my0;
        tw[vi][2] = mx0 * my1;
        tw[vi][3] = mx1 * my1;
    }

    // per-batch base pointers for each view's feature map
    const float4* v1b = fv1 + (size_t)b * NH * NW * (NC / 4);
    const float4* v2b = fv2 + ((size_t)NB - (size_t)b) * 0;  // placeholder (fixed below)
    (void)v2b;
    const float4* v2  = (const float4*)(ft + (((size_t)(2 * NB + b)) * NH) * NW * NC);
    const float4* v1  = (const float4*)(ft + (((size_t)(1 * NB + b)) * NH) * NW * NC);
    (void)v1b;

    float sq1 = 0.f, sq2 = 0.f;

#pragma unroll 4
    for (int c = 0; c < NC / 4; ++c) {
        float4 rc = f0[c];

        float4 t0 = v1[ti[0][0] + c];
        float4 t1 = v1[ti[0][1] + c];
        float4 t2 = v1[ti[0][2] + c];
        float4 t3 = v1[ti[0][3] + c];
        rc.x -= t0.x * tw[0][0] + t1.x * tw[0][1] + t2.x * tw[0][2] + t3.x * tw[0][3];
        rc.y -= t0.y * tw[0][0] + t1.y * tw[0][1] + t2.y * tw[0][2] + t3.y * tw[0][3];
        rc.z -= t0.z * tw[0][0] + t1.z * tw[0][1] + t2.z * tw[0][2] + t3.z * tw[0][3];
        rc.w -= t0.w * tw[0][0] + t1.w * tw[0][1] + t2.w * tw[0][2] + t3.w * tw[0][3];
        sq1 += rc.x * rc.x + rc.y * rc.y + rc.z * rc.z + rc.w * rc.w;

        float4 u0 = v2[ti[1][0] + c];
        float4 u1 = v2[ti[1][1] + c];
        float4 u2 = v2[ti[1][2] + c];
        float4 u3 = v2[ti[1][3] + c];
        rc.x -= u0.x * tw[1][0] + u1.x * tw[1][1] + u2.x * tw[1][2] + u3.x * tw[1][3];
        rc.y -= u0.y * tw[1][0] + u1.y * tw[1][1] + u2.y * tw[1][2] + u3.y * tw[1][3];
        rc.z -= u0.z * tw[1][0] + u1.z * tw[1][1] + u2.z * tw[1][2] + u3.z * tw[1][3];
        rc.w -= u0.w * tw[1][0] + u1.w * tw[1][1] + u2.w * tw[1][2] + u3.w * tw[1][3];
        sq2 += rc.x * rc.x + rc.y * rc.y + rc.z * rc.z + rc.w * rc.w;
    }

    // per-pixel cost, scaled; then one wave reduce + one atomic per wave
    float cl = (sqrtf(sq1) + sqrtf(sq2)) * (0.5f / (float)(NH * NW));
#pragma unroll
    for (int m = 1; m < 64; m <<= 1) cl += __shfl_xor(cl, m, 64);
    if ((tid & 63) == 0) atomicAdd(&cost[b * NSC + ns], cl);
}

// ---------------------------------------------------------------------------
// Finalize: softmax over NS per batch, weighted sum with scale_hypo -> out[B]
// ---------------------------------------------------------------------------
__global__ void finalize_kernel(const float* __restrict__ cost,
                                const float* __restrict__ scale,
                                float* __restrict__ out) {
    int tid = threadIdx.x;
    if (tid >= NB * NSC) return;
    int b = tid >> 5;
    int ns = tid & 31;
    float c = cost[b * NSC + ns];
    float sv = scale[b * NSC + ns];

    float m = c;
#pragma unroll
    for (int mk = 1; mk < 32; mk <<= 1) m = fmaxf(m, __shfl_xor(m, mk, 64));
    float e = __expf(c - m);
    float sum = e;
#pragma unroll
    for (int mk = 1; mk < 32; mk <<= 1) sum += __shfl_xor(sum, mk, 64);
    float val = (e / sum) * sv;
#pragma unroll
    for (int mk = 1; mk < 32; mk <<= 1) val += __shfl_xor(val, mk, 64);
    if (ns == 0) out[b] = val;
}

// ---------------------------------------------------------------------------
extern "C" void kernel_launch(void* const* d_in, const int* in_sizes, int n_in,
                              void* d_out, int out_size, void* d_ws, size_t ws_size,
                              hipStream_t stream) {
    const float* features   = (const float*)d_in[0];  // (V,B,C,H,W)
    const float* intrinsics = (const float*)d_in[1];  // (V,B,3,3)
    const float* cam2world  = (const float*)d_in[2];  // (V,B,4,4)
    const float* scale_hypo = (const float*)d_in[3];  // (B,NS)
    const float* depth_init = (const float*)d_in[4];  // (B,H,W)
    float* out = (float*)d_out;                       // (B,)

    // workspace layout
    float* ft   = (float*)d_ws;                               // V*B*H*W*C floats
    float* rt   = ft + (size_t)NV * NB * NH * NW * NC;        // 2*B*12 floats
    float* cost = rt + 2 * NB * 12;                           // B*NS floats

    hipMemsetAsync(cost, 0, NB * NSC * sizeof(float), stream);

    setup_kernel<<<1, 64, 0, stream>>>(intrinsics, cam2world, rt);

    dim3 tgrid(NH, NV * NB);
    transpose_kernel<<<tgrid, 256, 0, stream>>>(features, ft);

    dim3 cgrid(NH / 2, NSC, NB);
    cost_kernel<<<cgrid, 256, 0, stream>>>(ft, depth_init, scale_hypo, rt, cost);

    finalize_kernel<<<1, 64, 0, stream>>>(cost, scale_hypo, out);
}

// Round 4
// 256.817 us; speedup vs baseline: 1.8814x; 1.8814x over previous
//
#include <hip/hip_runtime.h>
#include <math.h>

// Problem constants (from reference): V=3, B=2, C=64, NS=32, H=128, W=128
constexpr int NV = 3;
constexpr int NB = 2;
constexpr int NC = 64;
constexpr int NSC = 32;
constexpr int NH = 128;
constexpr int NW = 128;
constexpr int NSB = 4;   // ns values per thread

// ---------------------------------------------------------------------------
// DPP helpers (VALU cross-lane, no DS pipe).
// row_shr:N = 0x110+N ; row_bcast:15 = 0x142 ; row_bcast:31 = 0x143
// ---------------------------------------------------------------------------
template <int CTRL>
__device__ __forceinline__ float dpp_add(float x) {
    int s = __builtin_amdgcn_update_dpp(0, __float_as_int(x), CTRL, 0xf, 0xf, true);
    return x + __int_as_float(s);
}
// after this, lane 15 of each 16-lane row holds the row sum
__device__ __forceinline__ float row_sum16(float x) {
    x = dpp_add<0x111>(x);   // row_shr:1
    x = dpp_add<0x112>(x);   // row_shr:2
    x = dpp_add<0x114>(x);   // row_shr:4
    x = dpp_add<0x118>(x);   // row_shr:8
    return x;
}
// combine the 4 row-tail values (lanes 15/31/47/63) -> total in lane 63
__device__ __forceinline__ float cross_row_sum(float x) {
    x = dpp_add<0x142>(x);   // row_bcast:15
    x = dpp_add<0x143>(x);   // row_bcast:31
    return x;
}

// ---------------------------------------------------------------------------
// 4x4 inverse (adjugate, double precision) — mirrors jnp.linalg.inv fidelity
// ---------------------------------------------------------------------------
__device__ void inv4x4(const double* m, double* out) {
    double inv[16];
    inv[0]  =  m[5]*m[10]*m[15] - m[5]*m[11]*m[14] - m[9]*m[6]*m[15] + m[9]*m[7]*m[14] + m[13]*m[6]*m[11] - m[13]*m[7]*m[10];
    inv[4]  = -m[4]*m[10]*m[15] + m[4]*m[11]*m[14] + m[8]*m[6]*m[15] - m[8]*m[7]*m[14] - m[12]*m[6]*m[11] + m[12]*m[7]*m[10];
    inv[8]  =  m[4]*m[9]*m[15]  - m[4]*m[11]*m[13] - m[8]*m[5]*m[15] + m[8]*m[7]*m[13] + m[12]*m[5]*m[11] - m[12]*m[7]*m[9];
    inv[12] = -m[4]*m[9]*m[14]  + m[4]*m[10]*m[13] + m[8]*m[5]*m[14] - m[8]*m[6]*m[13] - m[12]*m[5]*m[10] + m[12]*m[6]*m[9];
    inv[1]  = -m[1]*m[10]*m[15] + m[1]*m[11]*m[14] + m[9]*m[2]*m[15] - m[9]*m[3]*m[14] - m[13]*m[2]*m[11] + m[13]*m[3]*m[10];
    inv[5]  =  m[0]*m[10]*m[15] - m[0]*m[11]*m[14] - m[8]*m[2]*m[15] + m[8]*m[3]*m[14] + m[12]*m[2]*m[11] - m[12]*m[3]*m[10];
    inv[9]  = -m[0]*m[9]*m[15]  + m[0]*m[11]*m[13] + m[8]*m[1]*m[15] - m[8]*m[3]*m[13] - m[12]*m[1]*m[11] + m[12]*m[3]*m[9];
    inv[13] =  m[0]*m[9]*m[14]  - m[0]*m[10]*m[13] - m[8]*m[1]*m[14] + m[8]*m[2]*m[13] + m[12]*m[1]*m[10] - m[12]*m[2]*m[9];
    inv[2]  =  m[1]*m[6]*m[15]  - m[1]*m[7]*m[14]  - m[5]*m[2]*m[15] + m[5]*m[3]*m[14] + m[13]*m[2]*m[7]  - m[13]*m[3]*m[6];
    inv[6]  = -m[0]*m[6]*m[15]  + m[0]*m[7]*m[14]  + m[4]*m[2]*m[15] - m[4]*m[3]*m[14] - m[12]*m[2]*m[7]  + m[12]*m[3]*m[6];
    inv[10] =  m[0]*m[5]*m[15]  - m[0]*m[7]*m[13]  - m[4]*m[1]*m[15] + m[4]*m[3]*m[13] + m[12]*m[1]*m[7]  - m[12]*m[3]*m[5];
    inv[14] = -m[0]*m[5]*m[14]  + m[0]*m[6]*m[13]  + m[4]*m[1]*m[14] - m[4]*m[2]*m[13] - m[12]*m[1]*m[6]  + m[12]*m[2]*m[5];
    inv[3]  = -m[1]*m[6]*m[11]  + m[1]*m[7]*m[10]  + m[5]*m[2]*m[11] - m[5]*m[3]*m[10] - m[9]*m[2]*m[7]   + m[9]*m[3]*m[6];
    inv[7]  =  m[0]*m[6]*m[11]  - m[0]*m[7]*m[10]  - m[4]*m[2]*m[11] + m[4]*m[3]*m[10] + m[8]*m[2]*m[7]   - m[8]*m[3]*m[6];
    inv[11] = -m[0]*m[5]*m[11]  + m[0]*m[7]*m[9]   + m[4]*m[1]*m[11] - m[4]*m[3]*m[9]  - m[8]*m[1]*m[7]   + m[8]*m[3]*m[5];
    inv[15] =  m[0]*m[5]*m[10]  - m[0]*m[6]*m[9]   - m[4]*m[1]*m[10] + m[4]*m[2]*m[9]  + m[8]*m[1]*m[6]   - m[8]*m[2]*m[5];
    double det = m[0]*inv[0] + m[1]*inv[4] + m[2]*inv[8] + m[3]*inv[12];
    det = 1.0 / det;
    for (int i = 0; i < 16; ++i) out[i] = inv[i] * det;
}

__device__ void mat4mul(const double* a, const double* b, double* o) {
    for (int i = 0; i < 4; ++i)
        for (int j = 0; j < 4; ++j) {
            double s = 0.0;
            for (int k = 0; k < 4; ++k) s += a[i*4+k] * b[k*4+j];
            o[i*4+j] = s;
        }
}

// ---------------------------------------------------------------------------
// Setup: per (src view, batch) rot(3x3)+trans(3) of the homography
// ---------------------------------------------------------------------------
__global__ void setup_kernel(const float* __restrict__ intr,
                             const float* __restrict__ c2w,
                             float* __restrict__ rt) {
    int t = threadIdx.x;
    if (t >= 2 * NB) return;
    int vi = t >> 1;
    int b  = t & 1;
    int v  = vi + 1;

    double src_c2w[16], ref_c2w[16];
    for (int i = 0; i < 16; ++i) {
        src_c2w[i] = (double)c2w[(v * NB + b) * 16 + i];
        ref_c2w[i] = (double)c2w[(0 * NB + b) * 16 + i];
    }
    double src_w2c[16], ref_w2c[16];
    inv4x4(src_c2w, src_w2c);
    inv4x4(ref_c2w, ref_w2c);

    double srcP[16], refP[16];
    for (int i = 0; i < 16; ++i) { srcP[i] = src_w2c[i]; refP[i] = ref_w2c[i]; }
    for (int r = 0; r < 3; ++r)
        for (int c = 0; c < 3; ++c) {
            srcP[r*4+c] = (double)intr[(v * NB + b) * 9 + r*3 + c];
            refP[r*4+c] = (double)intr[(0 * NB + b) * 9 + r*3 + c];
        }

    double M1[16], M2[16], M2inv[16];
    mat4mul(srcP, src_w2c, M1);
    mat4mul(refP, ref_w2c, M2);
    inv4x4(M2, M2inv);
    double proj[16];
    mat4mul(M1, M2inv, proj);

    float* o = rt + (vi * NB + b) * 12;
    o[0] = (float)proj[0];  o[1] = (float)proj[1];  o[2]  = (float)proj[2];
    o[3] = (float)proj[4];  o[4] = (float)proj[5];  o[5]  = (float)proj[6];
    o[6] = (float)proj[8];  o[7] = (float)proj[9];  o[8]  = (float)proj[10];
    o[9] = (float)proj[3];  o[10] = (float)proj[7]; o[11] = (float)proj[11];
}

// ---------------------------------------------------------------------------
// Transpose features (V*B, C, H, W) -> (V*B, H, W, C)
// ---------------------------------------------------------------------------
__global__ __launch_bounds__(256) void transpose_kernel(const float* __restrict__ in,
                                                        float* __restrict__ out) {
    __shared__ float tile[NC][NW + 1];
    const int y  = blockIdx.x;
    const int vb = blockIdx.y;

    for (int i = threadIdx.x; i < NC * NW; i += 256) {
        int c = i >> 7;
        int x = i & (NW - 1);
        tile[c][x] = in[((size_t)(vb * NC + c) * NH + y) * NW + x];
    }
    __syncthreads();
    float* dst = out + ((size_t)vb * NH + y) * NW * NC;
    for (int i = threadIdx.x; i < NC * NW; i += 256) {
        int x = i >> 6;
        int c = i & (NC - 1);
        dst[x * NC + c] = tile[c][x];
    }
}

// ---------------------------------------------------------------------------
// Main cost kernel v4: 16-lane group = 1 pixel (float4 of channels per lane,
// all loads group-coalesced 256B), wave = 4 pixels, block = 16 pixels.
// Each thread processes NSB=4 consecutive ns hypotheses (independent chains,
// f0 amortized). Channel reduce via DPP VALU (no DS shuffles). One LDS
// block-reduce, 4 atomics per block.
// Grid: (H*W/16, NS/NSB, B).
// ---------------------------------------------------------------------------
__global__ __launch_bounds__(256) void cost_kernel(
    const float* __restrict__ ft,     // (V, B, H, W, C) transposed features
    const float* __restrict__ depth,  // (B, H, W)
    const float* __restrict__ scale,  // (B, NS)
    const float* __restrict__ rt,     // (2, B, 12)
    float* __restrict__ cost)         // (B, NS) -- pre-zeroed
{
    const int tid  = threadIdx.x;
    const int lane = tid & 63;
    const int wv   = tid >> 6;       // wave id in block (0..3)
    const int grp  = lane >> 4;      // pixel group in wave (0..3)
    const int gl   = lane & 15;      // float4 slot in the 64-ch record
    const int nsg  = blockIdx.y;     // ns group
    const int b    = blockIdx.z;

    const int p = blockIdx.x * 16 + wv * 4 + grp;   // pixel index in image
    const int x = p & (NW - 1);
    const int y = p >> 7;
    const float fx = (float)x;
    const float fy = (float)y;

    const float d0 = depth[(b * NH + y) * NW + x];

    const float4* f0p = (const float4*)(ft + (((size_t)(0 * NB + b) * NH + y) * NW + x) * NC);
    const float4 f0 = f0p[gl];
    const float4* v1 = (const float4*)(ft + ((size_t)(1 * NB + b) * NH) * NW * NC);
    const float4* v2 = (const float4*)(ft + ((size_t)(2 * NB + b) * NH) * NW * NC);

    float R0[12], R1[12];
#pragma unroll
    for (int k = 0; k < 12; ++k) {
        R0[k] = rt[(0 * NB + b) * 12 + k];
        R1[k] = rt[(1 * NB + b) * 12 + k];
    }

    const float CXY = 64.0f / 63.5f;  // fold of the grid-normalize chain

    __shared__ float red[4][NSB];     // [wave][nsub]
    float outv[NSB];

#pragma unroll
    for (int nsub = 0; nsub < NSB; ++nsub) {
        const float s = scale[b * NSC + nsg * NSB + nsub];
        const float d = d0 * s;

        int   ti[2][4];
        float tw[2][4];
#pragma unroll
        for (int vi = 0; vi < 2; ++vi) {
            const float* R = vi ? R1 : R0;
            float px = (R[0] * fx + R[1] * fy + R[2]) * d + R[9];
            float py = (R[3] * fx + R[4] * fy + R[5]) * d + R[10];
            float pz = (R[6] * fx + R[7] * fy + R[8]) * d + R[11];
            float invz = __builtin_amdgcn_rcpf(pz);
            float ix = (px * invz) * CXY - 0.5f;
            float iy = (py * invz) * CXY - 0.5f;

            float x0f = floorf(ix), y0f = floorf(iy);
            float wx1 = ix - x0f, wx0 = 1.f - wx1;
            float wy1 = iy - y0f, wy0 = 1.f - wy1;

            float mx0 = (x0f >= 0.f  && x0f <= 127.f) ? wx0 : 0.f;
            float mx1 = (x0f >= -1.f && x0f <= 126.f) ? wx1 : 0.f;
            float my0 = (y0f >= 0.f  && y0f <= 127.f) ? wy0 : 0.f;
            float my1 = (y0f >= -1.f && y0f <= 126.f) ? wy1 : 0.f;

            int xi0 = (int)fminf(fmaxf(x0f, 0.f), 127.f);
            int yi0 = (int)fminf(fmaxf(y0f, 0.f), 127.f);
            int xi1 = (int)fminf(fmaxf(x0f + 1.f, 0.f), 127.f);
            int yi1 = (int)fminf(fmaxf(y0f + 1.f, 0.f), 127.f);

            ti[vi][0] = (yi0 * NW + xi0) * (NC / 4) + gl;
            ti[vi][1] = (yi0 * NW + xi1) * (NC / 4) + gl;
            ti[vi][2] = (yi1 * NW + xi0) * (NC / 4) + gl;
            ti[vi][3] = (yi1 * NW + xi1) * (NC / 4) + gl;
            tw[vi][0] = mx0 * my0;
            tw[vi][1] = mx1 * my0;
            tw[vi][2] = mx0 * my1;
            tw[vi][3] = mx1 * my1;
        }

        float4 r = f0;

        float4 t0 = v1[ti[0][0]];
        float4 t1 = v1[ti[0][1]];
        float4 t2 = v1[ti[0][2]];
        float4 t3 = v1[ti[0][3]];
        r.x -= t0.x * tw[0][0] + t1.x * tw[0][1] + t2.x * tw[0][2] + t3.x * tw[0][3];
        r.y -= t0.y * tw[0][0] + t1.y * tw[0][1] + t2.y * tw[0][2] + t3.y * tw[0][3];
        r.z -= t0.z * tw[0][0] + t1.z * tw[0][1] + t2.z * tw[0][2] + t3.z * tw[0][3];
        r.w -= t0.w * tw[0][0] + t1.w * tw[0][1] + t2.w * tw[0][2] + t3.w * tw[0][3];
        float sq1 = r.x * r.x + r.y * r.y + r.z * r.z + r.w * r.w;

        float4 u0 = v2[ti[1][0]];
        float4 u1 = v2[ti[1][1]];
        float4 u2 = v2[ti[1][2]];
        float4 u3 = v2[ti[1][3]];
        r.x -= u0.x * tw[1][0] + u1.x * tw[1][1] + u2.x * tw[1][2] + u3.x * tw[1][3];
        r.y -= u0.y * tw[1][0] + u1.y * tw[1][1] + u2.y * tw[1][2] + u3.y * tw[1][3];
        r.z -= u0.z * tw[1][0] + u1.z * tw[1][1] + u2.z * tw[1][2] + u3.z * tw[1][3];
        r.w -= u0.w * tw[1][0] + u1.w * tw[1][1] + u2.w * tw[1][2] + u3.w * tw[1][3];
        float sq2 = r.x * r.x + r.y * r.y + r.z * r.z + r.w * r.w;

        // reduce over the 16-lane group (VALU/DPP): row tails hold sums
        sq1 = row_sum16(sq1);
        sq2 = row_sum16(sq2);
        float sv = sqrtf(sq1) + sqrtf(sq2);   // valid on lanes 15/31/47/63
        outv[nsub] = cross_row_sum(sv);       // total over 4 pixels in lane 63
    }

    if (lane == 63) {
#pragma unroll
        for (int nsub = 0; nsub < NSB; ++nsub) red[wv][nsub] = outv[nsub];
    }
    __syncthreads();
    if (tid < NSB) {
        float t = red[0][tid] + red[1][tid] + red[2][tid] + red[3][tid];
        atomicAdd(&cost[b * NSC + nsg * NSB + tid], t * (0.5f / (float)(NH * NW)));
    }
}

// ---------------------------------------------------------------------------
// Finalize: softmax over NS per batch, weighted sum with scale_hypo -> out[B]
// ---------------------------------------------------------------------------
__global__ void finalize_kernel(const float* __restrict__ cost,
                                const float* __restrict__ scale,
                                float* __restrict__ out) {
    int tid = threadIdx.x;
    if (tid >= NB * NSC) return;
    int b = tid >> 5;
    int ns = tid & 31;
    float c = cost[b * NSC + ns];
    float sv = scale[b * NSC + ns];

    float m = c;
#pragma unroll
    for (int mk = 1; mk < 32; mk <<= 1) m = fmaxf(m, __shfl_xor(m, mk, 64));
    float e = __expf(c - m);
    float sum = e;
#pragma unroll
    for (int mk = 1; mk < 32; mk <<= 1) sum += __shfl_xor(sum, mk, 64);
    float val = (e / sum) * sv;
#pragma unroll
    for (int mk = 1; mk < 32; mk <<= 1) val += __shfl_xor(val, mk, 64);
    if (ns == 0) out[b] = val;
}

// ---------------------------------------------------------------------------
extern "C" void kernel_launch(void* const* d_in, const int* in_sizes, int n_in,
                              void* d_out, int out_size, void* d_ws, size_t ws_size,
                              hipStream_t stream) {
    const float* features   = (const float*)d_in[0];  // (V,B,C,H,W)
    const float* intrinsics = (const float*)d_in[1];  // (V,B,3,3)
    const float* cam2world  = (const float*)d_in[2];  // (V,B,4,4)
    const float* scale_hypo = (const float*)d_in[3];  // (B,NS)
    const float* depth_init = (const float*)d_in[4];  // (B,H,W)
    float* out = (float*)d_out;                       // (B,)

    // workspace layout
    float* ft   = (float*)d_ws;                               // V*B*H*W*C floats
    float* rt   = ft + (size_t)NV * NB * NH * NW * NC;        // 2*B*12 floats
    float* cost = rt + 2 * NB * 12;                           // B*NS floats

    hipMemsetAsync(cost, 0, NB * NSC * sizeof(float), stream);

    setup_kernel<<<1, 64, 0, stream>>>(intrinsics, cam2world, rt);

    dim3 tgrid(NH, NV * NB);
    transpose_kernel<<<tgrid, 256, 0, stream>>>(features, ft);

    dim3 cgrid(NH * NW / 16, NSC / NSB, NB);
    cost_kernel<<<cgrid, 256, 0, stream>>>(ft, depth_init, scale_hypo, rt, cost);

    finalize_kernel<<<1, 64, 0, stream>>>(cost, scale_hypo, out);
}

// Round 5
// 187.794 us; speedup vs baseline: 2.5730x; 1.3675x over previous
//
#include <hip/hip_runtime.h>
#include <math.h>

// Problem constants (from reference): V=3, B=2, C=64, NS=32, H=128, W=128
constexpr int NV = 3;
constexpr int NB = 2;
constexpr int NC = 64;
constexpr int NSC = 32;
constexpr int NH = 128;
constexpr int NW = 128;
constexpr int NSB = 4;   // ns values per thread

// ---------------------------------------------------------------------------
// DPP helpers (VALU cross-lane, no DS pipe).
// row_shr:N = 0x110+N ; row_bcast:15 = 0x142 ; row_bcast:31 = 0x143
// ---------------------------------------------------------------------------
template <int CTRL>
__device__ __forceinline__ float dpp_add(float x) {
    int s = __builtin_amdgcn_update_dpp(0, __float_as_int(x), CTRL, 0xf, 0xf, true);
    return x + __int_as_float(s);
}

// bf16x2 (one dword) -> two fp32
__device__ __forceinline__ void conv8(const uint4& q, float* o) {
    o[0] = __uint_as_float(q.x << 16);
    o[1] = __uint_as_float(q.x & 0xFFFF0000u);
    o[2] = __uint_as_float(q.y << 16);
    o[3] = __uint_as_float(q.y & 0xFFFF0000u);
    o[4] = __uint_as_float(q.z << 16);
    o[5] = __uint_as_float(q.z & 0xFFFF0000u);
    o[6] = __uint_as_float(q.w << 16);
    o[7] = __uint_as_float(q.w & 0xFFFF0000u);
}

__device__ __forceinline__ unsigned int f32_to_bf16_rne(float f) {
    unsigned int u = __float_as_uint(f);
    u += 0x7fffu + ((u >> 16) & 1u);
    return u >> 16;
}

// ---------------------------------------------------------------------------
// 4x4 inverse (adjugate, double precision) — mirrors jnp.linalg.inv fidelity
// ---------------------------------------------------------------------------
__device__ void inv4x4(const double* m, double* out) {
    double inv[16];
    inv[0]  =  m[5]*m[10]*m[15] - m[5]*m[11]*m[14] - m[9]*m[6]*m[15] + m[9]*m[7]*m[14] + m[13]*m[6]*m[11] - m[13]*m[7]*m[10];
    inv[4]  = -m[4]*m[10]*m[15] + m[4]*m[11]*m[14] + m[8]*m[6]*m[15] - m[8]*m[7]*m[14] - m[12]*m[6]*m[11] + m[12]*m[7]*m[10];
    inv[8]  =  m[4]*m[9]*m[15]  - m[4]*m[11]*m[13] - m[8]*m[5]*m[15] + m[8]*m[7]*m[13] + m[12]*m[5]*m[11] - m[12]*m[7]*m[9];
    inv[12] = -m[4]*m[9]*m[14]  + m[4]*m[10]*m[13] + m[8]*m[5]*m[14] - m[8]*m[6]*m[13] - m[12]*m[5]*m[10] + m[12]*m[6]*m[9];
    inv[1]  = -m[1]*m[10]*m[15] + m[1]*m[11]*m[14] + m[9]*m[2]*m[15] - m[9]*m[3]*m[14] - m[13]*m[2]*m[11] + m[13]*m[3]*m[10];
    inv[5]  =  m[0]*m[10]*m[15] - m[0]*m[11]*m[14] - m[8]*m[2]*m[15] + m[8]*m[3]*m[14] + m[12]*m[2]*m[11] - m[12]*m[3]*m[10];
    inv[9]  = -m[0]*m[9]*m[15]  + m[0]*m[11]*m[13] + m[8]*m[1]*m[15] - m[8]*m[3]*m[13] - m[12]*m[1]*m[11] + m[12]*m[3]*m[9];
    inv[13] =  m[0]*m[9]*m[14]  - m[0]*m[10]*m[13] - m[8]*m[1]*m[14] + m[8]*m[2]*m[13] + m[12]*m[1]*m[10] - m[12]*m[2]*m[9];
    inv[2]  =  m[1]*m[6]*m[15]  - m[1]*m[7]*m[14]  - m[5]*m[2]*m[15] + m[5]*m[3]*m[14] + m[13]*m[2]*m[7]  - m[13]*m[3]*m[6];
    inv[6]  = -m[0]*m[6]*m[15]  + m[0]*m[7]*m[14]  + m[4]*m[2]*m[15] - m[4]*m[3]*m[14] - m[12]*m[2]*m[7]  + m[12]*m[3]*m[6];
    inv[10] =  m[0]*m[5]*m[15]  - m[0]*m[7]*m[13]  - m[4]*m[1]*m[15] + m[4]*m[3]*m[13] + m[12]*m[1]*m[7]  - m[12]*m[3]*m[5];
    inv[14] = -m[0]*m[5]*m[14]  + m[0]*m[6]*m[13]  + m[4]*m[1]*m[14] - m[4]*m[2]*m[13] - m[12]*m[1]*m[6]  + m[12]*m[2]*m[5];
    inv[3]  = -m[1]*m[6]*m[11]  + m[1]*m[7]*m[10]  + m[5]*m[2]*m[11] - m[5]*m[3]*m[10] - m[9]*m[2]*m[7]   + m[9]*m[3]*m[6];
    inv[7]  =  m[0]*m[6]*m[11]  - m[0]*m[7]*m[10]  - m[4]*m[2]*m[11] + m[4]*m[3]*m[10] + m[8]*m[2]*m[7]   - m[8]*m[3]*m[6];
    inv[11] = -m[0]*m[5]*m[11]  + m[0]*m[7]*m[9]   + m[4]*m[1]*m[11] - m[4]*m[3]*m[9]  - m[8]*m[1]*m[7]   + m[8]*m[3]*m[5];
    inv[15] =  m[0]*m[5]*m[10]  - m[0]*m[6]*m[9]   - m[4]*m[1]*m[10] + m[4]*m[2]*m[9]  + m[8]*m[1]*m[6]   - m[8]*m[2]*m[5];
    double det = m[0]*inv[0] + m[1]*inv[4] + m[2]*inv[8] + m[3]*inv[12];
    det = 1.0 / det;
    for (int i = 0; i < 16; ++i) out[i] = inv[i] * det;
}

__device__ void mat4mul(const double* a, const double* b, double* o) {
    for (int i = 0; i < 4; ++i)
        for (int j = 0; j < 4; ++j) {
            double s = 0.0;
            for (int k = 0; k < 4; ++k) s += a[i*4+k] * b[k*4+j];
            o[i*4+j] = s;
        }
}

// ---------------------------------------------------------------------------
// Setup: per (src view, batch) rot(3x3)+trans(3) of the homography.
// Also zeroes the cost accumulator (threads 4..4+B*NS).
// ---------------------------------------------------------------------------
__global__ void setup_kernel(const float* __restrict__ intr,
                             const float* __restrict__ c2w,
                             float* __restrict__ rt,
                             float* __restrict__ cost) {
    int t = threadIdx.x;
    if (t >= 4 && t < 4 + NB * NSC) cost[t - 4] = 0.f;
    if (t >= 2 * NB) return;
    int vi = t >> 1;
    int b  = t & 1;
    int v  = vi + 1;

    double src_c2w[16], ref_c2w[16];
    for (int i = 0; i < 16; ++i) {
        src_c2w[i] = (double)c2w[(v * NB + b) * 16 + i];
        ref_c2w[i] = (double)c2w[(0 * NB + b) * 16 + i];
    }
    double src_w2c[16], ref_w2c[16];
    inv4x4(src_c2w, src_w2c);
    inv4x4(ref_c2w, ref_w2c);

    double srcP[16], refP[16];
    for (int i = 0; i < 16; ++i) { srcP[i] = src_w2c[i]; refP[i] = ref_w2c[i]; }
    for (int r = 0; r < 3; ++r)
        for (int c = 0; c < 3; ++c) {
            srcP[r*4+c] = (double)intr[(v * NB + b) * 9 + r*3 + c];
            refP[r*4+c] = (double)intr[(0 * NB + b) * 9 + r*3 + c];
        }

    double M1[16], M2[16], M2inv[16];
    mat4mul(srcP, src_w2c, M1);
    mat4mul(refP, ref_w2c, M2);
    inv4x4(M2, M2inv);
    double proj[16];
    mat4mul(M1, M2inv, proj);

    float* o = rt + (vi * NB + b) * 12;
    o[0] = (float)proj[0];  o[1] = (float)proj[1];  o[2]  = (float)proj[2];
    o[3] = (float)proj[4];  o[4] = (float)proj[5];  o[5]  = (float)proj[6];
    o[6] = (float)proj[8];  o[7] = (float)proj[9];  o[8]  = (float)proj[10];
    o[9] = (float)proj[3];  o[10] = (float)proj[7]; o[11] = (float)proj[11];
}

// ---------------------------------------------------------------------------
// Transpose + bf16 compress: (V*B, C, H, W) fp32 -> (V*B, H, W, C) bf16.
// One block per (vb, y) row. Writes uint (2 packed bf16 channels) per thread.
// ---------------------------------------------------------------------------
__global__ __launch_bounds__(256) void transpose_kernel(const float* __restrict__ in,
                                                        unsigned int* __restrict__ out) {
    __shared__ float tile[NC][NW + 1];
    const int y  = blockIdx.x;
    const int vb = blockIdx.y;

    for (int i = threadIdx.x; i < NC * NW; i += 256) {
        int c = i >> 7;
        int x = i & (NW - 1);
        tile[c][x] = in[((size_t)(vb * NC + c) * NH + y) * NW + x];
    }
    __syncthreads();
    // dst: per pixel x a record of 64 bf16 = 32 uints
    unsigned int* dst = out + ((size_t)vb * NH + y) * NW * (NC / 2);
    for (int i = threadIdx.x; i < NW * (NC / 2); i += 256) {
        int x  = i >> 5;         // /32
        int cp = i & 31;         // channel pair
        unsigned int lo = f32_to_bf16_rne(tile[2 * cp][x]);
        unsigned int hi = f32_to_bf16_rne(tile[2 * cp + 1][x]);
        dst[x * (NC / 2) + cp] = lo | (hi << 16);
    }
}

// ---------------------------------------------------------------------------
// Main cost kernel v5: 8-lane group = 1 pixel; lane holds 8 bf16 channels
// (uint4 = 16B = exactly 1/8 of a 128B record). Wave = 8 pixels, block = 32.
// Each thread handles NSB=4 ns hypotheses (independent chains, f0 amortized).
// All loads fully coalesced (one wave instr = 8 records). DPP-only reduce.
// Grid: (H*W/32, NS/NSB, B).
// ---------------------------------------------------------------------------
__global__ __launch_bounds__(256) void cost_kernel(
    const unsigned int* __restrict__ ftb, // (V, B, H, W, C) bf16 features
    const float* __restrict__ depth,      // (B, H, W)
    const float* __restrict__ scale,      // (B, NS)
    const float* __restrict__ rt,         // (2, B, 12)
    float* __restrict__ cost)             // (B, NS) -- zeroed by setup
{
    const int tid  = threadIdx.x;
    const int lane = tid & 63;
    const int wv   = tid >> 6;       // wave id in block (0..3)
    const int grp  = lane >> 3;      // pixel group in wave (0..7)
    const int gl   = lane & 7;       // uint4 slot in the 128B record
    const int nsg  = blockIdx.y;     // ns group
    const int b    = blockIdx.z;

    const int p = blockIdx.x * 32 + wv * 8 + grp;   // pixel index in image
    const int x = p & (NW - 1);
    const int y = p >> 7;
    const float fx = (float)x;
    const float fy = (float)y;

    const float d0 = depth[(b * NH + y) * NW + x];

    // base pointers (uint4 = 16B units; record = 8 uint4)
    const uint4* f0q = (const uint4*)(ftb) + ((size_t)(0 * NB + b) * NH * NW + p) * 8 + gl;
    const uint4* v1q = (const uint4*)(ftb) + ((size_t)(1 * NB + b) * NH * NW) * 8 + gl;
    const uint4* v2q = (const uint4*)(ftb) + ((size_t)(2 * NB + b) * NH * NW) * 8 + gl;

    float f0c[8];
    conv8(*f0q, f0c);

    float R0[12], R1[12];
#pragma unroll
    for (int k = 0; k < 12; ++k) {
        R0[k] = rt[(0 * NB + b) * 12 + k];
        R1[k] = rt[(1 * NB + b) * 12 + k];
    }
    // ns-invariant parts of the projection
    const float ax0 = R0[0] * fx + R0[1] * fy + R0[2];
    const float ay0 = R0[3] * fx + R0[4] * fy + R0[5];
    const float az0 = R0[6] * fx + R0[7] * fy + R0[8];
    const float ax1 = R1[0] * fx + R1[1] * fy + R1[2];
    const float ay1 = R1[3] * fx + R1[4] * fy + R1[5];
    const float az1 = R1[6] * fx + R1[7] * fy + R1[8];

    const float CXY = 64.0f / 63.5f;  // fold of the grid-normalize chain

    __shared__ float red[4][NSB];
    float outv[NSB];

#pragma unroll
    for (int nsub = 0; nsub < NSB; ++nsub) {
        const float s = scale[b * NSC + nsg * NSB + nsub];
        const float d = d0 * s;

        int   ti[2][4];
        float tw[2][4];
#pragma unroll
        for (int vi = 0; vi < 2; ++vi) {
            float px = (vi ? ax1 : ax0) * d + (vi ? R1[9]  : R0[9]);
            float py = (vi ? ay1 : ay0) * d + (vi ? R1[10] : R0[10]);
            float pz = (vi ? az1 : az0) * d + (vi ? R1[11] : R0[11]);
            float invz = __builtin_amdgcn_rcpf(pz);
            float ix = (px * invz) * CXY - 0.5f;
            float iy = (py * invz) * CXY - 0.5f;

            float x0f = floorf(ix), y0f = floorf(iy);
            float wx1 = ix - x0f, wx0 = 1.f - wx1;
            float wy1 = iy - y0f, wy0 = 1.f - wy1;

            float mx0 = (x0f >= 0.f  && x0f <= 127.f) ? wx0 : 0.f;
            float mx1 = (x0f >= -1.f && x0f <= 126.f) ? wx1 : 0.f;
            float my0 = (y0f >= 0.f  && y0f <= 127.f) ? wy0 : 0.f;
            float my1 = (y0f >= -1.f && y0f <= 126.f) ? wy1 : 0.f;

            int xi0 = (int)fminf(fmaxf(x0f, 0.f), 127.f);
            int yi0 = (int)fminf(fmaxf(y0f, 0.f), 127.f);
            // neighbor offsets degenerate to 0 at borders (weight is 0 there)
            int xo = (x0f >= 0.f && x0f <= 126.f) ? 8 : 0;          // +1 col, uint4 units
            int yo = (y0f >= 0.f && y0f <= 126.f) ? NW * 8 : 0;     // +1 row

            int base = (yi0 * NW + xi0) * 8;
            ti[vi][0] = base;
            ti[vi][1] = base + xo;
            ti[vi][2] = base + yo;
            ti[vi][3] = base + yo + xo;
            tw[vi][0] = mx0 * my0;
            tw[vi][1] = mx1 * my0;
            tw[vi][2] = mx0 * my1;
            tw[vi][3] = mx1 * my1;
        }

        // issue all 8 tap loads (deep MLP), then combine
        uint4 t0 = v1q[ti[0][0]];
        uint4 t1 = v1q[ti[0][1]];
        uint4 t2 = v1q[ti[0][2]];
        uint4 t3 = v1q[ti[0][3]];
        uint4 u0 = v2q[ti[1][0]];
        uint4 u1 = v2q[ti[1][1]];
        uint4 u2 = v2q[ti[1][2]];
        uint4 u3 = v2q[ti[1][3]];

        float c8[8], acc[8], r[8];

        conv8(t0, acc);
#pragma unroll
        for (int k = 0; k < 8; ++k) acc[k] *= tw[0][0];
        conv8(t1, c8);
#pragma unroll
        for (int k = 0; k < 8; ++k) acc[k] += c8[k] * tw[0][1];
        conv8(t2, c8);
#pragma unroll
        for (int k = 0; k < 8; ++k) acc[k] += c8[k] * tw[0][2];
        conv8(t3, c8);
#pragma unroll
        for (int k = 0; k < 8; ++k) acc[k] += c8[k] * tw[0][3];

        float sq1 = 0.f;
#pragma unroll
        for (int k = 0; k < 8; ++k) {
            r[k] = f0c[k] - acc[k];
            sq1 += r[k] * r[k];
        }

        conv8(u0, acc);
#pragma unroll
        for (int k = 0; k < 8; ++k) acc[k] *= tw[1][0];
        conv8(u1, c8);
#pragma unroll
        for (int k = 0; k < 8; ++k) acc[k] += c8[k] * tw[1][1];
        conv8(u2, c8);
#pragma unroll
        for (int k = 0; k < 8; ++k) acc[k] += c8[k] * tw[1][2];
        conv8(u3, c8);
#pragma unroll
        for (int k = 0; k < 8; ++k) acc[k] += c8[k] * tw[1][3];

        float sq2 = 0.f;
#pragma unroll
        for (int k = 0; k < 8; ++k) {
            r[k] -= acc[k];
            sq2 += r[k] * r[k];
        }

        // 8-lane group reduce (prefix via row_shr; tails at lanes 7,15,...)
        sq1 = dpp_add<0x111>(sq1);
        sq1 = dpp_add<0x112>(sq1);
        sq1 = dpp_add<0x114>(sq1);
        sq2 = dpp_add<0x111>(sq2);
        sq2 = dpp_add<0x112>(sq2);
        sq2 = dpp_add<0x114>(sq2);
        float sv = sqrtf(sq1) + sqrtf(sq2);   // valid on lanes 7,15,23,...,63
        // combine the 8 group tails -> wave total in lane 63
        sv = dpp_add<0x118>(sv);   // row_shr:8  : lane15=g01, 31=g23, 47=g45, 63=g67
        sv = dpp_add<0x142>(sv);   // row_bcast:15: lane31=g0123
        sv = dpp_add<0x143>(sv);   // row_bcast:31: lane63=total
        outv[nsub] = sv;
    }

    if (lane == 63) {
#pragma unroll
        for (int nsub = 0; nsub < NSB; ++nsub) red[wv][nsub] = outv[nsub];
    }
    __syncthreads();
    if (tid < NSB) {
        float t = red[0][tid] + red[1][tid] + red[2][tid] + red[3][tid];
        atomicAdd(&cost[b * NSC + nsg * NSB + tid], t * (0.5f / (float)(NH * NW)));
    }
}

// ---------------------------------------------------------------------------
// Finalize: softmax over NS per batch, weighted sum with scale_hypo -> out[B]
// ---------------------------------------------------------------------------
__global__ void finalize_kernel(const float* __restrict__ cost,
                                const float* __restrict__ scale,
                                float* __restrict__ out) {
    int tid = threadIdx.x;
    if (tid >= NB * NSC) return;
    int b = tid >> 5;
    int ns = tid & 31;
    float c = cost[b * NSC + ns];
    float sv = scale[b * NSC + ns];

    float m = c;
#pragma unroll
    for (int mk = 1; mk < 32; mk <<= 1) m = fmaxf(m, __shfl_xor(m, mk, 64));
    float e = __expf(c - m);
    float sum = e;
#pragma unroll
    for (int mk = 1; mk < 32; mk <<= 1) sum += __shfl_xor(sum, mk, 64);
    float val = (e / sum) * sv;
#pragma unroll
    for (int mk = 1; mk < 32; mk <<= 1) val += __shfl_xor(val, mk, 64);
    if (ns == 0) out[b] = val;
}

// ---------------------------------------------------------------------------
extern "C" void kernel_launch(void* const* d_in, const int* in_sizes, int n_in,
                              void* d_out, int out_size, void* d_ws, size_t ws_size,
                              hipStream_t stream) {
    const float* features   = (const float*)d_in[0];  // (V,B,C,H,W)
    const float* intrinsics = (const float*)d_in[1];  // (V,B,3,3)
    const float* cam2world  = (const float*)d_in[2];  // (V,B,4,4)
    const float* scale_hypo = (const float*)d_in[3];  // (B,NS)
    const float* depth_init = (const float*)d_in[4];  // (B,H,W)
    float* out = (float*)d_out;                       // (B,)

    // workspace layout
    unsigned int* ftb = (unsigned int*)d_ws;                      // V*B*H*W*C/2 uints (bf16 pairs)
    float* rt   = (float*)(ftb + (size_t)NV * NB * NH * NW * (NC / 2));
    float* cost = rt + 2 * NB * 12;                               // B*NS floats

    setup_kernel<<<1, 128, 0, stream>>>(intrinsics, cam2world, rt, cost);

    dim3 tgrid(NH, NV * NB);
    transpose_kernel<<<tgrid, 256, 0, stream>>>(features, ftb);

    dim3 cgrid(NH * NW / 32, NSC / NSB, NB);
    cost_kernel<<<cgrid, 256, 0, stream>>>(ftb, depth_init, scale_hypo, rt, cost);

    finalize_kernel<<<1, 64, 0, stream>>>(cost, scale_hypo, out);
}

// Round 6
// 166.017 us; speedup vs baseline: 2.9105x; 1.1312x over previous
//
#include <hip/hip_runtime.h>
#include <math.h>

// Problem constants (from reference): V=3, B=2, C=64, NS=32, H=128, W=128
constexpr int NV = 3;
constexpr int NB = 2;
constexpr int NC = 64;
constexpr int NSC = 32;
constexpr int NH = 128;
constexpr int NW = 128;
constexpr int NSB = 4;   // ns values per thread

typedef _Float16 h2_t __attribute__((ext_vector_type(2)));

// ---------------------------------------------------------------------------
// DPP helpers (VALU cross-lane, no DS pipe).
// ---------------------------------------------------------------------------
template <int CTRL>
__device__ __forceinline__ float dpp_add(float x) {
    int s = __builtin_amdgcn_update_dpp(0, __float_as_int(x), CTRL, 0xf, 0xf, true);
    return x + __int_as_float(s);
}

__device__ __forceinline__ float dot2acc(h2_t a, float acc) {
#if __has_builtin(__builtin_amdgcn_fdot2)
    return __builtin_amdgcn_fdot2(a, a, acc, false);
#else
    float x = (float)a.x, y = (float)a.y;
    return acc + x * x + y * y;
#endif
}

// ---------------------------------------------------------------------------
// 4x4 inverse (adjugate, double precision) — mirrors jnp.linalg.inv fidelity
// ---------------------------------------------------------------------------
__device__ void inv4x4(const double* m, double* out) {
    double inv[16];
    inv[0]  =  m[5]*m[10]*m[15] - m[5]*m[11]*m[14] - m[9]*m[6]*m[15] + m[9]*m[7]*m[14] + m[13]*m[6]*m[11] - m[13]*m[7]*m[10];
    inv[4]  = -m[4]*m[10]*m[15] + m[4]*m[11]*m[14] + m[8]*m[6]*m[15] - m[8]*m[7]*m[14] - m[12]*m[6]*m[11] + m[12]*m[7]*m[10];
    inv[8]  =  m[4]*m[9]*m[15]  - m[4]*m[11]*m[13] - m[8]*m[5]*m[15] + m[8]*m[7]*m[13] + m[12]*m[5]*m[11] - m[12]*m[7]*m[9];
    inv[12] = -m[4]*m[9]*m[14]  + m[4]*m[10]*m[13] + m[8]*m[5]*m[14] - m[8]*m[6]*m[13] - m[12]*m[5]*m[10] + m[12]*m[6]*m[9];
    inv[1]  = -m[1]*m[10]*m[15] + m[1]*m[11]*m[14] + m[9]*m[2]*m[15] - m[9]*m[3]*m[14] - m[13]*m[2]*m[11] + m[13]*m[3]*m[10];
    inv[5]  =  m[0]*m[10]*m[15] - m[0]*m[11]*m[14] - m[8]*m[2]*m[15] + m[8]*m[3]*m[14] + m[12]*m[2]*m[11] - m[12]*m[3]*m[10];
    inv[9]  = -m[0]*m[9]*m[15]  + m[0]*m[11]*m[13] + m[8]*m[1]*m[15] - m[8]*m[3]*m[13] - m[12]*m[1]*m[11] + m[12]*m[3]*m[9];
    inv[13] =  m[0]*m[9]*m[14]  - m[0]*m[10]*m[13] - m[8]*m[1]*m[14] + m[8]*m[2]*m[13] + m[12]*m[1]*m[10] - m[12]*m[2]*m[9];
    inv[2]  =  m[1]*m[6]*m[15]  - m[1]*m[7]*m[14]  - m[5]*m[2]*m[15] + m[5]*m[3]*m[14] + m[13]*m[2]*m[7]  - m[13]*m[3]*m[6];
    inv[6]  = -m[0]*m[6]*m[15]  + m[0]*m[7]*m[14]  + m[4]*m[2]*m[15] - m[4]*m[3]*m[14] - m[12]*m[2]*m[7]  + m[12]*m[3]*m[6];
    inv[10] =  m[0]*m[5]*m[15]  - m[0]*m[7]*m[13]  - m[4]*m[1]*m[15] + m[4]*m[3]*m[13] + m[12]*m[1]*m[7]  - m[12]*m[3]*m[5];
    inv[14] = -m[0]*m[5]*m[14]  + m[0]*m[6]*m[13]  + m[4]*m[1]*m[14] - m[4]*m[2]*m[13] - m[12]*m[1]*m[6]  + m[12]*m[2]*m[5];
    inv[3]  = -m[1]*m[6]*m[11]  + m[1]*m[7]*m[10]  + m[5]*m[2]*m[11] - m[5]*m[3]*m[10] - m[9]*m[2]*m[7]   + m[9]*m[3]*m[6];
    inv[7]  =  m[0]*m[6]*m[11]  - m[0]*m[7]*m[10]  - m[4]*m[2]*m[11] + m[4]*m[3]*m[10] + m[8]*m[2]*m[7]   - m[8]*m[3]*m[6];
    inv[11] = -m[0]*m[5]*m[11]  + m[0]*m[7]*m[9]   + m[4]*m[1]*m[11] - m[4]*m[3]*m[9]  - m[8]*m[1]*m[7]   + m[8]*m[3]*m[5];
    inv[15] =  m[0]*m[5]*m[10]  - m[0]*m[6]*m[9]   - m[4]*m[1]*m[10] + m[4]*m[2]*m[9]  + m[8]*m[1]*m[6]   - m[8]*m[2]*m[5];
    double det = m[0]*inv[0] + m[1]*inv[4] + m[2]*inv[8] + m[3]*inv[12];
    det = 1.0 / det;
    for (int i = 0; i < 16; ++i) out[i] = inv[i] * det;
}

__device__ void mat4mul(const double* a, const double* b, double* o) {
    for (int i = 0; i < 4; ++i)
        for (int j = 0; j < 4; ++j) {
            double s = 0.0;
            for (int k = 0; k < 4; ++k) s += a[i*4+k] * b[k*4+j];
            o[i*4+j] = s;
        }
}

// ---------------------------------------------------------------------------
// Transpose + f16 compress: (V*B, C, H, W) fp32 -> (V*B, H*W, C) f16.
// One block per (vb, y) row. Block (0,0) additionally computes the
// homography rot/trans (threads 0..3) and zeroes cost (threads 4..67).
// ---------------------------------------------------------------------------
__global__ __launch_bounds__(256) void transpose_kernel(const float* __restrict__ in,
                                                        unsigned int* __restrict__ out,
                                                        const float* __restrict__ intr,
                                                        const float* __restrict__ c2w,
                                                        float* __restrict__ rt,
                                                        float* __restrict__ cost) {
    __shared__ float tile[NC][NW + 1];
    const int y  = blockIdx.x;
    const int vb = blockIdx.y;

    for (int i = threadIdx.x; i < NC * NW; i += 256) {
        int c = i >> 7;
        int x = i & (NW - 1);
        tile[c][x] = in[((size_t)(vb * NC + c) * NH + y) * NW + x];
    }
    __syncthreads();
    // dst: per pixel a record of 64 f16 = 32 uints
    unsigned int* dst = out + ((size_t)vb * NH + y) * NW * (NC / 2);
    for (int i = threadIdx.x; i < NW * (NC / 2); i += 256) {
        int x  = i >> 5;         // /32
        int cp = i & 31;         // channel pair
        h2_t h = { (_Float16)tile[2 * cp][x], (_Float16)tile[2 * cp + 1][x] };
        dst[x * (NC / 2) + cp] = __builtin_bit_cast(unsigned int, h);
    }

    // ---- fused setup (one block only) ----
    if (blockIdx.x == 0 && blockIdx.y == 0) {
        int t = threadIdx.x;
        if (t >= 4 && t < 4 + NB * NSC) cost[t - 4] = 0.f;
        if (t < 2 * NB) {
            int vi = t >> 1;
            int b  = t & 1;
            int v  = vi + 1;

            double src_c2w[16], ref_c2w[16];
            for (int i = 0; i < 16; ++i) {
                src_c2w[i] = (double)c2w[(v * NB + b) * 16 + i];
                ref_c2w[i] = (double)c2w[(0 * NB + b) * 16 + i];
            }
            double src_w2c[16], ref_w2c[16];
            inv4x4(src_c2w, src_w2c);
            inv4x4(ref_c2w, ref_w2c);

            double srcP[16], refP[16];
            for (int i = 0; i < 16; ++i) { srcP[i] = src_w2c[i]; refP[i] = ref_w2c[i]; }
            for (int r = 0; r < 3; ++r)
                for (int c = 0; c < 3; ++c) {
                    srcP[r*4+c] = (double)intr[(v * NB + b) * 9 + r*3 + c];
                    refP[r*4+c] = (double)intr[(0 * NB + b) * 9 + r*3 + c];
                }

            double M1[16], M2[16], M2inv[16];
            mat4mul(srcP, src_w2c, M1);
            mat4mul(refP, ref_w2c, M2);
            inv4x4(M2, M2inv);
            double proj[16];
            mat4mul(M1, M2inv, proj);

            float* o = rt + (vi * NB + b) * 12;
            o[0] = (float)proj[0];  o[1] = (float)proj[1];  o[2]  = (float)proj[2];
            o[3] = (float)proj[4];  o[4] = (float)proj[5];  o[5]  = (float)proj[6];
            o[6] = (float)proj[8];  o[7] = (float)proj[9];  o[8]  = (float)proj[10];
            o[9] = (float)proj[3];  o[10] = (float)proj[7]; o[11] = (float)proj[11];
        }
    }
}

// ---------------------------------------------------------------------------
// Main cost kernel v6: 8-lane group = 1 pixel; lane holds 8 f16 channels
// (uint4 = 16B = 1/8 of a 128B record). Wave = 8 pixels, block = 32 pixels.
// NSB=4 ns hypotheses per thread. Bilinear combine + residual entirely in
// packed half2 FMAs (f0 folded in via negated weights); squared-sum via
// v_dot2_f32_f16 into f32. DPP-only reduce, 4 atomics per block.
// Grid: (H*W/32, NS/NSB, B).
// ---------------------------------------------------------------------------
__global__ __launch_bounds__(256) void cost_kernel(
    const unsigned int* __restrict__ ftb, // (V, B, H*W, C) f16 features
    const float* __restrict__ depth,      // (B, H, W)
    const float* __restrict__ scale,      // (B, NS)
    const float* __restrict__ rt,         // (2, B, 12)
    float* __restrict__ cost)             // (B, NS) -- zeroed by transpose
{
    const int tid  = threadIdx.x;
    const int lane = tid & 63;
    const int wv   = tid >> 6;       // wave id in block (0..3)
    const int grp  = lane >> 3;      // pixel group in wave (0..7)
    const int gl   = lane & 7;       // uint4 slot in the 128B record
    const int nsg  = blockIdx.y;     // ns group
    const int b    = blockIdx.z;

    const int p = blockIdx.x * 32 + wv * 8 + grp;   // pixel index in image
    const int x = p & (NW - 1);
    const int y = p >> 7;
    const float fx = (float)x;
    const float fy = (float)y;

    const float d0 = depth[(b * NH + y) * NW + x];

    // base pointers (uint4 = 16B units; record = 8 uint4)
    const uint4* f0q = (const uint4*)(ftb) + ((size_t)(0 * NB + b) * NH * NW + p) * 8 + gl;
    const uint4* v1q = (const uint4*)(ftb) + ((size_t)(1 * NB + b) * NH * NW) * 8 + gl;
    const uint4* v2q = (const uint4*)(ftb) + ((size_t)(2 * NB + b) * NH * NW) * 8 + gl;

    const uint4 f0u = *f0q;
    const h2_t* f0h = (const h2_t*)&f0u;

    float R0[12], R1[12];
#pragma unroll
    for (int k = 0; k < 12; ++k) {
        R0[k] = rt[(0 * NB + b) * 12 + k];
        R1[k] = rt[(1 * NB + b) * 12 + k];
    }
    // ns-invariant parts of the projection
    const float ax0 = R0[0] * fx + R0[1] * fy + R0[2];
    const float ay0 = R0[3] * fx + R0[4] * fy + R0[5];
    const float az0 = R0[6] * fx + R0[7] * fy + R0[8];
    const float ax1 = R1[0] * fx + R1[1] * fy + R1[2];
    const float ay1 = R1[3] * fx + R1[4] * fy + R1[5];
    const float az1 = R1[6] * fx + R1[7] * fy + R1[8];

    const float CXY = 64.0f / 63.5f;  // fold of the grid-normalize chain

    __shared__ float red[4][NSB];
    float outv[NSB];

#pragma unroll
    for (int nsub = 0; nsub < NSB; ++nsub) {
        const float s = scale[b * NSC + nsg * NSB + nsub];
        const float d = d0 * s;

        int   ti[2][4];
        float tw[2][4];
#pragma unroll
        for (int vi = 0; vi < 2; ++vi) {
            float px = (vi ? ax1 : ax0) * d + (vi ? R1[9]  : R0[9]);
            float py = (vi ? ay1 : ay0) * d + (vi ? R1[10] : R0[10]);
            float pz = (vi ? az1 : az0) * d + (vi ? R1[11] : R0[11]);
            float invz = __builtin_amdgcn_rcpf(pz);
            float ix = (px * invz) * CXY - 0.5f;
            float iy = (py * invz) * CXY - 0.5f;

            float x0f = floorf(ix), y0f = floorf(iy);
            float wx1 = ix - x0f, wx0 = 1.f - wx1;
            float wy1 = iy - y0f, wy0 = 1.f - wy1;

            float mx0 = (x0f >= 0.f  && x0f <= 127.f) ? wx0 : 0.f;
            float mx1 = (x0f >= -1.f && x0f <= 126.f) ? wx1 : 0.f;
            float my0 = (y0f >= 0.f  && y0f <= 127.f) ? wy0 : 0.f;
            float my1 = (y0f >= -1.f && y0f <= 126.f) ? wy1 : 0.f;

            int xi0 = (int)fminf(fmaxf(x0f, 0.f), 127.f);
            int yi0 = (int)fminf(fmaxf(y0f, 0.f), 127.f);
            // neighbor offsets degenerate to 0 at borders (weight is 0 there)
            int xo = (x0f >= 0.f && x0f <= 126.f) ? 8 : 0;          // +1 col, uint4 units
            int yo = (y0f >= 0.f && y0f <= 126.f) ? NW * 8 : 0;     // +1 row

            int base = (yi0 * NW + xi0) * 8;
            ti[vi][0] = base;
            ti[vi][1] = base + xo;
            ti[vi][2] = base + yo;
            ti[vi][3] = base + yo + xo;
            tw[vi][0] = mx0 * my0;
            tw[vi][1] = mx1 * my0;
            tw[vi][2] = mx0 * my1;
            tw[vi][3] = mx1 * my1;
        }

        // issue all 8 tap loads (deep MLP), then combine
        uint4 t0 = v1q[ti[0][0]];
        uint4 t1 = v1q[ti[0][1]];
        uint4 t2 = v1q[ti[0][2]];
        uint4 t3 = v1q[ti[0][3]];
        uint4 u0 = v2q[ti[1][0]];
        uint4 u1 = v2q[ti[1][1]];
        uint4 u2 = v2q[ti[1][2]];
        uint4 u3 = v2q[ti[1][3]];

        // negated weights as half2 splats (r = f0 - sum w_t * tap_t)
        _Float16 w00 = (_Float16)(-tw[0][0]), w01 = (_Float16)(-tw[0][1]);
        _Float16 w02 = (_Float16)(-tw[0][2]), w03 = (_Float16)(-tw[0][3]);
        _Float16 w10 = (_Float16)(-tw[1][0]), w11 = (_Float16)(-tw[1][1]);
        _Float16 w12 = (_Float16)(-tw[1][2]), w13 = (_Float16)(-tw[1][3]);
        h2_t h00 = {w00, w00}, h01 = {w01, w01}, h02 = {w02, w02}, h03 = {w03, w03};
        h2_t h10 = {w10, w10}, h11 = {w11, w11}, h12 = {w12, w12}, h13 = {w13, w13};

        const h2_t* p0 = (const h2_t*)&t0;
        const h2_t* p1 = (const h2_t*)&t1;
        const h2_t* p2 = (const h2_t*)&t2;
        const h2_t* p3 = (const h2_t*)&t3;
        const h2_t* q0 = (const h2_t*)&u0;
        const h2_t* q1 = (const h2_t*)&u1;
        const h2_t* q2 = (const h2_t*)&u2;
        const h2_t* q3 = (const h2_t*)&u3;

        h2_t r[4];
        float sq1 = 0.f, sq2 = 0.f;
#pragma unroll
        for (int j = 0; j < 4; ++j) {
            h2_t rr = f0h[j];
            rr += p0[j] * h00;
            rr += p1[j] * h01;
            rr += p2[j] * h02;
            rr += p3[j] * h03;
            r[j] = rr;
            sq1 = dot2acc(rr, sq1);
        }
#pragma unroll
        for (int j = 0; j < 4; ++j) {
            h2_t rr = r[j];
            rr += q0[j] * h10;
            rr += q1[j] * h11;
            rr += q2[j] * h12;
            rr += q3[j] * h13;
            sq2 = dot2acc(rr, sq2);
        }

        // 8-lane group reduce (row_shr prefix; tails at lanes 7,15,...)
        sq1 = dpp_add<0x111>(sq1);
        sq1 = dpp_add<0x112>(sq1);
        sq1 = dpp_add<0x114>(sq1);
        sq2 = dpp_add<0x111>(sq2);
        sq2 = dpp_add<0x112>(sq2);
        sq2 = dpp_add<0x114>(sq2);
        float sv = sqrtf(sq1) + sqrtf(sq2);   // valid on lanes 7,15,...,63
        sv = dpp_add<0x118>(sv);   // row_shr:8
        sv = dpp_add<0x142>(sv);   // row_bcast:15
        sv = dpp_add<0x143>(sv);   // row_bcast:31 -> total in lane 63
        outv[nsub] = sv;
    }

    if (lane == 63) {
#pragma unroll
        for (int nsub = 0; nsub < NSB; ++nsub) red[wv][nsub] = outv[nsub];
    }
    __syncthreads();
    if (tid < NSB) {
        float t = red[0][tid] + red[1][tid] + red[2][tid] + red[3][tid];
        atomicAdd(&cost[b * NSC + nsg * NSB + tid], t * (0.5f / (float)(NH * NW)));
    }
}

// ---------------------------------------------------------------------------
// Finalize: softmax over NS per batch, weighted sum with scale_hypo -> out[B]
// ---------------------------------------------------------------------------
__global__ void finalize_kernel(const float* __restrict__ cost,
                                const float* __restrict__ scale,
                                float* __restrict__ out) {
    int tid = threadIdx.x;
    if (tid >= NB * NSC) return;
    int b = tid >> 5;
    int ns = tid & 31;
    float c = cost[b * NSC + ns];
    float sv = scale[b * NSC + ns];

    float m = c;
#pragma unroll
    for (int mk = 1; mk < 32; mk <<= 1) m = fmaxf(m, __shfl_xor(m, mk, 64));
    float e = __expf(c - m);
    float sum = e;
#pragma unroll
    for (int mk = 1; mk < 32; mk <<= 1) sum += __shfl_xor(sum, mk, 64);
    float val = (e / sum) * sv;
#pragma unroll
    for (int mk = 1; mk < 32; mk <<= 1) val += __shfl_xor(val, mk, 64);
    if (ns == 0) out[b] = val;
}

// ---------------------------------------------------------------------------
extern "C" void kernel_launch(void* const* d_in, const int* in_sizes, int n_in,
                              void* d_out, int out_size, void* d_ws, size_t ws_size,
                              hipStream_t stream) {
    const float* features   = (const float*)d_in[0];  // (V,B,C,H,W)
    const float* intrinsics = (const float*)d_in[1];  // (V,B,3,3)
    const float* cam2world  = (const float*)d_in[2];  // (V,B,4,4)
    const float* scale_hypo = (const float*)d_in[3];  // (B,NS)
    const float* depth_init = (const float*)d_in[4];  // (B,H,W)
    float* out = (float*)d_out;                       // (B,)

    // workspace layout
    unsigned int* ftb = (unsigned int*)d_ws;                      // V*B*H*W*C/2 uints (f16 pairs)
    float* rt   = (float*)(ftb + (size_t)NV * NB * NH * NW * (NC / 2));
    float* cost = rt + 2 * NB * 12;                               // B*NS floats

    dim3 tgrid(NH, NV * NB);
    transpose_kernel<<<tgrid, 256, 0, stream>>>(features, ftb, intrinsics, cam2world, rt, cost);

    dim3 cgrid(NH * NW / 32, NSC / NSB, NB);
    cost_kernel<<<cgrid, 256, 0, stream>>>(ftb, depth_init, scale_hypo, rt, cost);

    finalize_kernel<<<1, 64, 0, stream>>>(cost, scale_hypo, out);
}

// Round 7
// 156.648 us; speedup vs baseline: 3.0845x; 1.0598x over previous
//
#include <hip/hip_runtime.h>
#include <math.h>

// Problem constants (from reference): V=3, B=2, C=64, NS=32, H=128, W=128
constexpr int NV = 3;
constexpr int NB = 2;
constexpr int NC = 64;
constexpr int NSC = 32;
constexpr int NH = 128;
constexpr int NW = 128;
constexpr int NSB = 16;  // ns values per thread (ns-inner for epipolar locality)

typedef _Float16 h2_t __attribute__((ext_vector_type(2)));

// ---------------------------------------------------------------------------
// DPP helpers (VALU cross-lane, no DS pipe).
// ---------------------------------------------------------------------------
template <int CTRL>
__device__ __forceinline__ float dpp_add(float x) {
    int s = __builtin_amdgcn_update_dpp(0, __float_as_int(x), CTRL, 0xf, 0xf, true);
    return x + __int_as_float(s);
}

__device__ __forceinline__ float dot2acc(h2_t a, float acc) {
#if __has_builtin(__builtin_amdgcn_fdot2)
    return __builtin_amdgcn_fdot2(a, a, acc, false);
#else
    float x = (float)a.x, y = (float)a.y;
    return acc + x * x + y * y;
#endif
}

// ---------------------------------------------------------------------------
// 4x4 inverse (adjugate, double precision) — mirrors jnp.linalg.inv fidelity
// ---------------------------------------------------------------------------
__device__ void inv4x4(const double* m, double* out) {
    double inv[16];
    inv[0]  =  m[5]*m[10]*m[15] - m[5]*m[11]*m[14] - m[9]*m[6]*m[15] + m[9]*m[7]*m[14] + m[13]*m[6]*m[11] - m[13]*m[7]*m[10];
    inv[4]  = -m[4]*m[10]*m[15] + m[4]*m[11]*m[14] + m[8]*m[6]*m[15] - m[8]*m[7]*m[14] - m[12]*m[6]*m[11] + m[12]*m[7]*m[10];
    inv[8]  =  m[4]*m[9]*m[15]  - m[4]*m[11]*m[13] - m[8]*m[5]*m[15] + m[8]*m[7]*m[13] + m[12]*m[5]*m[11] - m[12]*m[7]*m[9];
    inv[12] = -m[4]*m[9]*m[14]  + m[4]*m[10]*m[13] + m[8]*m[5]*m[14] - m[8]*m[6]*m[13] - m[12]*m[5]*m[10] + m[12]*m[6]*m[9];
    inv[1]  = -m[1]*m[10]*m[15] + m[1]*m[11]*m[14] + m[9]*m[2]*m[15] - m[9]*m[3]*m[14] - m[13]*m[2]*m[11] + m[13]*m[3]*m[10];
    inv[5]  =  m[0]*m[10]*m[15] - m[0]*m[11]*m[14] - m[8]*m[2]*m[15] + m[8]*m[3]*m[14] + m[12]*m[2]*m[11] - m[12]*m[3]*m[10];
    inv[9]  = -m[0]*m[9]*m[15]  + m[0]*m[11]*m[13] + m[8]*m[1]*m[15] - m[8]*m[3]*m[13] - m[12]*m[1]*m[11] + m[12]*m[3]*m[9];
    inv[13] =  m[0]*m[9]*m[14]  - m[0]*m[10]*m[13] - m[8]*m[1]*m[14] + m[8]*m[2]*m[13] + m[12]*m[1]*m[10] - m[12]*m[2]*m[9];
    inv[2]  =  m[1]*m[6]*m[15]  - m[1]*m[7]*m[14]  - m[5]*m[2]*m[15] + m[5]*m[3]*m[14] + m[13]*m[2]*m[7]  - m[13]*m[3]*m[6];
    inv[6]  = -m[0]*m[6]*m[15]  + m[0]*m[7]*m[14]  + m[4]*m[2]*m[15] - m[4]*m[3]*m[14] - m[12]*m[2]*m[7]  + m[12]*m[3]*m[6];
    inv[10] =  m[0]*m[5]*m[15]  - m[0]*m[7]*m[13]  - m[4]*m[1]*m[15] + m[4]*m[3]*m[13] + m[12]*m[1]*m[7]  - m[12]*m[3]*m[5];
    inv[14] = -m[0]*m[5]*m[14]  + m[0]*m[6]*m[13]  + m[4]*m[1]*m[14] - m[4]*m[2]*m[13] - m[12]*m[1]*m[6]  + m[12]*m[2]*m[5];
    inv[3]  = -m[1]*m[6]*m[11]  + m[1]*m[7]*m[10]  + m[5]*m[2]*m[11] - m[5]*m[3]*m[10] - m[9]*m[2]*m[7]   + m[9]*m[3]*m[6];
    inv[7]  =  m[0]*m[6]*m[11]  - m[0]*m[7]*m[10]  - m[4]*m[2]*m[11] + m[4]*m[3]*m[10] + m[8]*m[2]*m[7]   - m[8]*m[3]*m[6];
    inv[11] = -m[0]*m[5]*m[11]  + m[0]*m[7]*m[9]   + m[4]*m[1]*m[11] - m[4]*m[3]*m[9]  - m[8]*m[1]*m[7]   + m[8]*m[3]*m[5];
    inv[15] =  m[0]*m[5]*m[10]  - m[0]*m[6]*m[9]   - m[4]*m[1]*m[10] + m[4]*m[2]*m[9]  + m[8]*m[1]*m[6]   - m[8]*m[2]*m[5];
    double det = m[0]*inv[0] + m[1]*inv[4] + m[2]*inv[8] + m[3]*inv[12];
    det = 1.0 / det;
    for (int i = 0; i < 16; ++i) out[i] = inv[i] * det;
}

__device__ void mat4mul(const double* a, const double* b, double* o) {
    for (int i = 0; i < 4; ++i)
        for (int j = 0; j < 4; ++j) {
            double s = 0.0;
            for (int k = 0; k < 4; ++k) s += a[i*4+k] * b[k*4+j];
            o[i*4+j] = s;
        }
}

// ---------------------------------------------------------------------------
// Transpose + f16 compress: (V*B, C, H, W) fp32 -> (V*B, H*W, C) f16.
// One block per (vb, y) row. Block (0,0) additionally computes the homography
// rot/trans (threads 0..3), zeroes cost (4..67) and the counter (68).
// ---------------------------------------------------------------------------
__global__ __launch_bounds__(256) void transpose_kernel(const float* __restrict__ in,
                                                        unsigned int* __restrict__ out,
                                                        const float* __restrict__ intr,
                                                        const float* __restrict__ c2w,
                                                        float* __restrict__ rt,
                                                        float* __restrict__ cost,
                                                        unsigned int* __restrict__ counter) {
    __shared__ float tile[NC][NW + 1];
    const int y  = blockIdx.x;
    const int vb = blockIdx.y;

    for (int i = threadIdx.x; i < NC * NW; i += 256) {
        int c = i >> 7;
        int x = i & (NW - 1);
        tile[c][x] = in[((size_t)(vb * NC + c) * NH + y) * NW + x];
    }
    __syncthreads();
    // dst: per pixel a record of 64 f16 = 32 uints
    unsigned int* dst = out + ((size_t)vb * NH + y) * NW * (NC / 2);
    for (int i = threadIdx.x; i < NW * (NC / 2); i += 256) {
        int x  = i >> 5;         // /32
        int cp = i & 31;         // channel pair
        h2_t h = { (_Float16)tile[2 * cp][x], (_Float16)tile[2 * cp + 1][x] };
        dst[x * (NC / 2) + cp] = __builtin_bit_cast(unsigned int, h);
    }

    // ---- fused setup (one block only) ----
    if (blockIdx.x == 0 && blockIdx.y == 0) {
        int t = threadIdx.x;
        if (t >= 4 && t < 4 + NB * NSC) cost[t - 4] = 0.f;
        if (t == 4 + NB * NSC) *counter = 0u;
        if (t < 2 * NB) {
            int vi = t >> 1;
            int b  = t & 1;
            int v  = vi + 1;

            double src_c2w[16], ref_c2w[16];
            for (int i = 0; i < 16; ++i) {
                src_c2w[i] = (double)c2w[(v * NB + b) * 16 + i];
                ref_c2w[i] = (double)c2w[(0 * NB + b) * 16 + i];
            }
            double src_w2c[16], ref_w2c[16];
            inv4x4(src_c2w, src_w2c);
            inv4x4(ref_c2w, ref_w2c);

            double srcP[16], refP[16];
            for (int i = 0; i < 16; ++i) { srcP[i] = src_w2c[i]; refP[i] = ref_w2c[i]; }
            for (int r = 0; r < 3; ++r)
                for (int c = 0; c < 3; ++c) {
                    srcP[r*4+c] = (double)intr[(v * NB + b) * 9 + r*3 + c];
                    refP[r*4+c] = (double)intr[(0 * NB + b) * 9 + r*3 + c];
                }

            double M1[16], M2[16], M2inv[16];
            mat4mul(srcP, src_w2c, M1);
            mat4mul(refP, ref_w2c, M2);
            inv4x4(M2, M2inv);
            double proj[16];
            mat4mul(M1, M2inv, proj);

            float* o = rt + (vi * NB + b) * 12;
            o[0] = (float)proj[0];  o[1] = (float)proj[1];  o[2]  = (float)proj[2];
            o[3] = (float)proj[4];  o[4] = (float)proj[5];  o[5]  = (float)proj[6];
            o[6] = (float)proj[8];  o[7] = (float)proj[9];  o[8]  = (float)proj[10];
            o[9] = (float)proj[3];  o[10] = (float)proj[7]; o[11] = (float)proj[11];
        }
    }
}

// ---------------------------------------------------------------------------
// Main cost kernel v7: 8-lane group = 1 pixel (uint4 = 8 f16 channels/lane).
// Wave = 8 pixels, block = 32 pixels. NSB=16 ns hypotheses per thread --
// consecutive ns sample nearly-identical tap locations (epipolar step <1px)
// so tap loads become L1 hits. Packed-half2 bilinear+residual, dot2 square,
// DPP-only reduce, per-nsub LDS store, 16 atomics per block.
// Last block (completion counter) runs the softmax finalize inline.
// Grid: (H*W/32, NS/NSB, B).
// ---------------------------------------------------------------------------
__global__ __launch_bounds__(256) void cost_kernel(
    const unsigned int* __restrict__ ftb, // (V, B, H*W, C) f16 features
    const float* __restrict__ depth,      // (B, H, W)
    const float* __restrict__ scale,      // (B, NS)
    const float* __restrict__ rt,         // (2, B, 12)
    float* __restrict__ cost,             // (B, NS) -- zeroed by transpose
    unsigned int* __restrict__ counter,   // completion counter -- zeroed
    float* __restrict__ outp,             // (B,) final output
    int total_blocks)
{
    const int tid  = threadIdx.x;
    const int lane = tid & 63;
    const int wv   = tid >> 6;       // wave id in block (0..3)
    const int grp  = lane >> 3;      // pixel group in wave (0..7)
    const int gl   = lane & 7;       // uint4 slot in the 128B record
    const int nsg  = blockIdx.y;     // ns group (0..NSC/NSB-1)
    const int b    = blockIdx.z;

    const int p = blockIdx.x * 32 + wv * 8 + grp;   // pixel index in image
    const int x = p & (NW - 1);
    const int y = p >> 7;
    const float fx = (float)x;
    const float fy = (float)y;

    const float d0 = depth[(b * NH + y) * NW + x];

    // base pointers (uint4 = 16B units; record = 8 uint4)
    const uint4* f0q = (const uint4*)(ftb) + ((size_t)(0 * NB + b) * NH * NW + p) * 8 + gl;
    const uint4* v1q = (const uint4*)(ftb) + ((size_t)(1 * NB + b) * NH * NW) * 8 + gl;
    const uint4* v2q = (const uint4*)(ftb) + ((size_t)(2 * NB + b) * NH * NW) * 8 + gl;

    const uint4 f0u = *f0q;
    const h2_t* f0h = (const h2_t*)&f0u;

    float R0[12], R1[12];
#pragma unroll
    for (int k = 0; k < 12; ++k) {
        R0[k] = rt[(0 * NB + b) * 12 + k];
        R1[k] = rt[(1 * NB + b) * 12 + k];
    }
    // ns-invariant parts of the projection
    const float ax0 = R0[0] * fx + R0[1] * fy + R0[2];
    const float ay0 = R0[3] * fx + R0[4] * fy + R0[5];
    const float az0 = R0[6] * fx + R0[7] * fy + R0[8];
    const float ax1 = R1[0] * fx + R1[1] * fy + R1[2];
    const float ay1 = R1[3] * fx + R1[4] * fy + R1[5];
    const float az1 = R1[6] * fx + R1[7] * fy + R1[8];

    const float CXY = 64.0f / 63.5f;  // fold of the grid-normalize chain

    __shared__ float red[4][NSB];

#pragma unroll 4
    for (int nsub = 0; nsub < NSB; ++nsub) {
        const float s = scale[b * NSC + nsg * NSB + nsub];
        const float d = d0 * s;

        int   ti[2][4];
        float tw[2][4];
#pragma unroll
        for (int vi = 0; vi < 2; ++vi) {
            float px = (vi ? ax1 : ax0) * d + (vi ? R1[9]  : R0[9]);
            float py = (vi ? ay1 : ay0) * d + (vi ? R1[10] : R0[10]);
            float pz = (vi ? az1 : az0) * d + (vi ? R1[11] : R0[11]);
            float invz = __builtin_amdgcn_rcpf(pz);
            float ix = (px * invz) * CXY - 0.5f;
            float iy = (py * invz) * CXY - 0.5f;

            float x0f = floorf(ix), y0f = floorf(iy);
            float wx1 = ix - x0f, wx0 = 1.f - wx1;
            float wy1 = iy - y0f, wy0 = 1.f - wy1;

            float mx0 = (x0f >= 0.f  && x0f <= 127.f) ? wx0 : 0.f;
            float mx1 = (x0f >= -1.f && x0f <= 126.f) ? wx1 : 0.f;
            float my0 = (y0f >= 0.f  && y0f <= 127.f) ? wy0 : 0.f;
            float my1 = (y0f >= -1.f && y0f <= 126.f) ? wy1 : 0.f;

            int xi0 = (int)fminf(fmaxf(x0f, 0.f), 127.f);
            int yi0 = (int)fminf(fmaxf(y0f, 0.f), 127.f);
            // neighbor offsets degenerate to 0 at borders (weight is 0 there)
            int xo = (x0f >= 0.f && x0f <= 126.f) ? 8 : 0;          // +1 col, uint4 units
            int yo = (y0f >= 0.f && y0f <= 126.f) ? NW * 8 : 0;     // +1 row

            int base = (yi0 * NW + xi0) * 8;
            ti[vi][0] = base;
            ti[vi][1] = base + xo;
            ti[vi][2] = base + yo;
            ti[vi][3] = base + yo + xo;
            tw[vi][0] = mx0 * my0;
            tw[vi][1] = mx1 * my0;
            tw[vi][2] = mx0 * my1;
            tw[vi][3] = mx1 * my1;
        }

        // issue all 8 tap loads (deep MLP), then combine
        uint4 t0 = v1q[ti[0][0]];
        uint4 t1 = v1q[ti[0][1]];
        uint4 t2 = v1q[ti[0][2]];
        uint4 t3 = v1q[ti[0][3]];
        uint4 u0 = v2q[ti[1][0]];
        uint4 u1 = v2q[ti[1][1]];
        uint4 u2 = v2q[ti[1][2]];
        uint4 u3 = v2q[ti[1][3]];

        // negated weights as half2 splats (r = f0 - sum w_t * tap_t)
        _Float16 w00 = (_Float16)(-tw[0][0]), w01 = (_Float16)(-tw[0][1]);
        _Float16 w02 = (_Float16)(-tw[0][2]), w03 = (_Float16)(-tw[0][3]);
        _Float16 w10 = (_Float16)(-tw[1][0]), w11 = (_Float16)(-tw[1][1]);
        _Float16 w12 = (_Float16)(-tw[1][2]), w13 = (_Float16)(-tw[1][3]);
        h2_t h00 = {w00, w00}, h01 = {w01, w01}, h02 = {w02, w02}, h03 = {w03, w03};
        h2_t h10 = {w10, w10}, h11 = {w11, w11}, h12 = {w12, w12}, h13 = {w13, w13};

        const h2_t* p0 = (const h2_t*)&t0;
        const h2_t* p1 = (const h2_t*)&t1;
        const h2_t* p2 = (const h2_t*)&t2;
        const h2_t* p3 = (const h2_t*)&t3;
        const h2_t* q0 = (const h2_t*)&u0;
        const h2_t* q1 = (const h2_t*)&u1;
        const h2_t* q2 = (const h2_t*)&u2;
        const h2_t* q3 = (const h2_t*)&u3;

        h2_t r[4];
        float sq1 = 0.f, sq2 = 0.f;
#pragma unroll
        for (int j = 0; j < 4; ++j) {
            h2_t rr = f0h[j];
            rr += p0[j] * h00;
            rr += p1[j] * h01;
            rr += p2[j] * h02;
            rr += p3[j] * h03;
            r[j] = rr;
            sq1 = dot2acc(rr, sq1);
        }
#pragma unroll
        for (int j = 0; j < 4; ++j) {
            h2_t rr = r[j];
            rr += q0[j] * h10;
            rr += q1[j] * h11;
            rr += q2[j] * h12;
            rr += q3[j] * h13;
            sq2 = dot2acc(rr, sq2);
        }

        // 8-lane group reduce (row_shr prefix; tails at lanes 7,15,...)
        sq1 = dpp_add<0x111>(sq1);
        sq1 = dpp_add<0x112>(sq1);
        sq1 = dpp_add<0x114>(sq1);
        sq2 = dpp_add<0x111>(sq2);
        sq2 = dpp_add<0x112>(sq2);
        sq2 = dpp_add<0x114>(sq2);
        float sv = sqrtf(sq1) + sqrtf(sq2);   // valid on lanes 7,15,...,63
        sv = dpp_add<0x118>(sv);   // row_shr:8
        sv = dpp_add<0x142>(sv);   // row_bcast:15
        sv = dpp_add<0x143>(sv);   // row_bcast:31 -> total in lane 63
        if (lane == 63) red[wv][nsub] = sv;
    }

    __syncthreads();
    if (tid < NSB) {
        float t = red[0][tid] + red[1][tid] + red[2][tid] + red[3][tid];
        atomicAdd(&cost[b * NSC + nsg * NSB + tid], t * (0.5f / (float)(NH * NW)));
        __threadfence();
    }
    __syncthreads();

    // ---- completion counter; last block runs the finalize ----
    __shared__ unsigned int lastflag;
    if (tid == 0) {
        unsigned int prev = atomicAdd(counter, 1u);
        lastflag = (prev == (unsigned int)(total_blocks - 1)) ? 1u : 0u;
    }
    __syncthreads();
    if (lastflag && tid < NB * NSC) {
        __threadfence();
        int bb = tid >> 5;
        int ns = tid & 31;
        float c  = atomicAdd(&cost[bb * NSC + ns], 0.0f);  // coherent read
        float sv = scale[bb * NSC + ns];

        float m = c;
#pragma unroll
        for (int mk = 1; mk < 32; mk <<= 1) m = fmaxf(m, __shfl_xor(m, mk, 64));
        float e = __expf(c - m);
        float sum = e;
#pragma unroll
        for (int mk = 1; mk < 32; mk <<= 1) sum += __shfl_xor(sum, mk, 64);
        float val = (e / sum) * sv;
#pragma unroll
        for (int mk = 1; mk < 32; mk <<= 1) val += __shfl_xor(val, mk, 64);
        if (ns == 0) outp[bb] = val;
    }
}

// ---------------------------------------------------------------------------
extern "C" void kernel_launch(void* const* d_in, const int* in_sizes, int n_in,
                              void* d_out, int out_size, void* d_ws, size_t ws_size,
                              hipStream_t stream) {
    const float* features   = (const float*)d_in[0];  // (V,B,C,H,W)
    const float* intrinsics = (const float*)d_in[1];  // (V,B,3,3)
    const float* cam2world  = (const float*)d_in[2];  // (V,B,4,4)
    const float* scale_hypo = (const float*)d_in[3];  // (B,NS)
    const float* depth_init = (const float*)d_in[4];  // (B,H,W)
    float* out = (float*)d_out;                       // (B,)

    // workspace layout
    unsigned int* ftb = (unsigned int*)d_ws;                      // V*B*H*W*C/2 uints (f16 pairs)
    float* rt   = (float*)(ftb + (size_t)NV * NB * NH * NW * (NC / 2));
    float* cost = rt + 2 * NB * 12;                               // B*NS floats
    unsigned int* counter = (unsigned int*)(cost + NB * NSC);

    dim3 tgrid(NH, NV * NB);
    transpose_kernel<<<tgrid, 256, 0, stream>>>(features, ftb, intrinsics, cam2world,
                                                rt, cost, counter);

    dim3 cgrid(NH * NW / 32, NSC / NSB, NB);
    int total_blocks = cgrid.x * cgrid.y * cgrid.z;
    cost_kernel<<<cgrid, 256, 0, stream>>>(ftb, depth_init, scale_hypo, rt,
                                           cost, counter, out, total_blocks);
}

// Round 9
// 156.558 us; speedup vs baseline: 3.0863x; 1.0006x over previous
//
#include <hip/hip_runtime.h>
#include <math.h>

// Problem constants (from reference): V=3, B=2, C=64, NS=32, H=128, W=128
constexpr int NV = 3;
constexpr int NB = 2;
constexpr int NC = 64;
constexpr int NSC = 32;
constexpr int NH = 128;
constexpr int NW = 128;
constexpr int NSB = 16;  // ns values per block-pass (ns-inner for epipolar locality)

typedef _Float16 h2_t __attribute__((ext_vector_type(2)));

// ---------------------------------------------------------------------------
// DPP helpers (VALU cross-lane, no DS pipe).
// ---------------------------------------------------------------------------
template <int CTRL>
__device__ __forceinline__ float dpp_add(float x) {
    int s = __builtin_amdgcn_update_dpp(0, __float_as_int(x), CTRL, 0xf, 0xf, true);
    return x + __int_as_float(s);
}

__device__ __forceinline__ float dot2acc(h2_t a, float acc) {
#if __has_builtin(__builtin_amdgcn_fdot2)
    return __builtin_amdgcn_fdot2(a, a, acc, false);
#else
    float x = (float)a.x, y = (float)a.y;
    return acc + x * x + y * y;
#endif
}

__device__ __forceinline__ h2_t pack2(float a, float b) {
#if __has_builtin(__builtin_amdgcn_cvt_pkrtz)
    return __builtin_bit_cast(h2_t, __builtin_amdgcn_cvt_pkrtz(a, b));
#else
    h2_t r = { (_Float16)a, (_Float16)b };
    return r;
#endif
}

// ---------------------------------------------------------------------------
// 4x4 inverse (adjugate, double precision) — mirrors jnp.linalg.inv fidelity
// ---------------------------------------------------------------------------
__device__ void inv4x4(const double* m, double* out) {
    double inv[16];
    inv[0]  =  m[5]*m[10]*m[15] - m[5]*m[11]*m[14] - m[9]*m[6]*m[15] + m[9]*m[7]*m[14] + m[13]*m[6]*m[11] - m[13]*m[7]*m[10];
    inv[4]  = -m[4]*m[10]*m[15] + m[4]*m[11]*m[14] + m[8]*m[6]*m[15] - m[8]*m[7]*m[14] - m[12]*m[6]*m[11] + m[12]*m[7]*m[10];
    inv[8]  =  m[4]*m[9]*m[15]  - m[4]*m[11]*m[13] - m[8]*m[5]*m[15] + m[8]*m[7]*m[13] + m[12]*m[5]*m[11] - m[12]*m[7]*m[9];
    inv[12] = -m[4]*m[9]*m[14]  + m[4]*m[10]*m[13] + m[8]*m[5]*m[14] - m[8]*m[6]*m[13] - m[12]*m[5]*m[10] + m[12]*m[6]*m[9];
    inv[1]  = -m[1]*m[10]*m[15] + m[1]*m[11]*m[14] + m[9]*m[2]*m[15] - m[9]*m[3]*m[14] - m[13]*m[2]*m[11] + m[13]*m[3]*m[10];
    inv[5]  =  m[0]*m[10]*m[15] - m[0]*m[11]*m[14] - m[8]*m[2]*m[15] + m[8]*m[3]*m[14] + m[12]*m[2]*m[11] - m[12]*m[3]*m[10];
    inv[9]  = -m[0]*m[9]*m[15]  + m[0]*m[11]*m[13] + m[8]*m[1]*m[15] - m[8]*m[3]*m[13] - m[12]*m[1]*m[11] + m[12]*m[3]*m[9];
    inv[13] =  m[0]*m[9]*m[14]  - m[0]*m[10]*m[13] - m[8]*m[1]*m[14] + m[8]*m[2]*m[13] + m[12]*m[1]*m[10] - m[12]*m[2]*m[9];
    inv[2]  =  m[1]*m[6]*m[15]  - m[1]*m[7]*m[14]  - m[5]*m[2]*m[15] + m[5]*m[3]*m[14] + m[13]*m[2]*m[7]  - m[13]*m[3]*m[6];
    inv[6]  = -m[0]*m[6]*m[15]  + m[0]*m[7]*m[14]  + m[4]*m[2]*m[15] - m[4]*m[3]*m[14] - m[12]*m[2]*m[7]  + m[12]*m[3]*m[6];
    inv[10] =  m[0]*m[5]*m[15]  - m[0]*m[7]*m[13]  - m[4]*m[1]*m[15] + m[4]*m[3]*m[13] + m[12]*m[1]*m[7]  - m[12]*m[3]*m[5];
    inv[14] = -m[0]*m[5]*m[14]  + m[0]*m[6]*m[13]  + m[4]*m[1]*m[14] - m[4]*m[2]*m[13] - m[12]*m[1]*m[6]  + m[12]*m[2]*m[5];
    inv[3]  = -m[1]*m[6]*m[11]  + m[1]*m[7]*m[10]  + m[5]*m[2]*m[11] - m[5]*m[3]*m[10] - m[9]*m[2]*m[7]   + m[9]*m[3]*m[6];
    inv[7]  =  m[0]*m[6]*m[11]  - m[0]*m[7]*m[10]  - m[4]*m[2]*m[11] + m[4]*m[3]*m[10] + m[8]*m[2]*m[7]   - m[8]*m[3]*m[6];
    inv[11] = -m[0]*m[5]*m[11]  + m[0]*m[7]*m[9]   + m[4]*m[1]*m[11] - m[4]*m[3]*m[9]  - m[8]*m[1]*m[7]   + m[8]*m[3]*m[5];
    inv[15] =  m[0]*m[5]*m[10]  - m[0]*m[6]*m[9]   - m[4]*m[1]*m[10] + m[4]*m[2]*m[9]  + m[8]*m[1]*m[6]   - m[8]*m[2]*m[5];
    double det = m[0]*inv[0] + m[1]*inv[4] + m[2]*inv[8] + m[3]*inv[12];
    det = 1.0 / det;
    for (int i = 0; i < 16; ++i) out[i] = inv[i] * det;
}

__device__ void mat4mul(const double* a, const double* b, double* o) {
    for (int i = 0; i < 4; ++i)
        for (int j = 0; j < 4; ++j) {
            double s = 0.0;
            for (int k = 0; k < 4; ++k) s += a[i*4+k] * b[k*4+j];
            o[i*4+j] = s;
        }
}

// ---------------------------------------------------------------------------
// Transpose + f16 compress: (V*B, C, H, W) fp32 -> (V*B, H*W, C) f16.
// One block per (vb, y) row. Block (0,0) additionally computes the homography
// rot/trans (threads 0..3), zeroes cost (4..67) and the counter (68).
// ---------------------------------------------------------------------------
__global__ __launch_bounds__(256) void transpose_kernel(const float* __restrict__ in,
                                                        unsigned int* __restrict__ out,
                                                        const float* __restrict__ intr,
                                                        const float* __restrict__ c2w,
                                                        float* __restrict__ rt,
                                                        float* __restrict__ cost,
                                                        unsigned int* __restrict__ counter) {
    __shared__ float tile[NC][NW + 1];
    const int y  = blockIdx.x;
    const int vb = blockIdx.y;

    for (int i = threadIdx.x; i < NC * NW; i += 256) {
        int c = i >> 7;
        int x = i & (NW - 1);
        tile[c][x] = in[((size_t)(vb * NC + c) * NH + y) * NW + x];
    }
    __syncthreads();
    // dst: per pixel a record of 64 f16 = 32 uints
    unsigned int* dst = out + ((size_t)vb * NH + y) * NW * (NC / 2);
    for (int i = threadIdx.x; i < NW * (NC / 2); i += 256) {
        int x  = i >> 5;         // /32
        int cp = i & 31;         // channel pair
        h2_t h = { (_Float16)tile[2 * cp][x], (_Float16)tile[2 * cp + 1][x] };
        dst[x * (NC / 2) + cp] = __builtin_bit_cast(unsigned int, h);
    }

    // ---- fused setup (one block only) ----
    if (blockIdx.x == 0 && blockIdx.y == 0) {
        int t = threadIdx.x;
        if (t >= 4 && t < 4 + NB * NSC) cost[t - 4] = 0.f;
        if (t == 4 + NB * NSC) *counter = 0u;
        if (t < 2 * NB) {
            int vi = t >> 1;
            int b  = t & 1;
            int v  = vi + 1;

            double src_c2w[16], ref_c2w[16];
            for (int i = 0; i < 16; ++i) {
                src_c2w[i] = (double)c2w[(v * NB + b) * 16 + i];
                ref_c2w[i] = (double)c2w[(0 * NB + b) * 16 + i];
            }
            double src_w2c[16], ref_w2c[16];
            inv4x4(src_c2w, src_w2c);
            inv4x4(ref_c2w, ref_w2c);

            double srcP[16], refP[16];
            for (int i = 0; i < 16; ++i) { srcP[i] = src_w2c[i]; refP[i] = ref_w2c[i]; }
            for (int r = 0; r < 3; ++r)
                for (int c = 0; c < 3; ++c) {
                    srcP[r*4+c] = (double)intr[(v * NB + b) * 9 + r*3 + c];
                    refP[r*4+c] = (double)intr[(0 * NB + b) * 9 + r*3 + c];
                }

            double M1[16], M2[16], M2inv[16];
            mat4mul(srcP, src_w2c, M1);
            mat4mul(refP, ref_w2c, M2);
            inv4x4(M2, M2inv);
            double proj[16];
            mat4mul(M1, M2inv, proj);

            float* o = rt + (vi * NB + b) * 12;
            o[0] = (float)proj[0];  o[1] = (float)proj[1];  o[2]  = (float)proj[2];
            o[3] = (float)proj[4];  o[4] = (float)proj[5];  o[5]  = (float)proj[6];
            o[6] = (float)proj[8];  o[7] = (float)proj[9];  o[8]  = (float)proj[10];
            o[9] = (float)proj[3];  o[10] = (float)proj[7]; o[11] = (float)proj[11];
        }
    }
}

// ---------------------------------------------------------------------------
// Geometry record: tap base index (uint4 units), packed neighbor offsets,
// 4 bilinear weights (f16, pre-negated). 16 B -> one ds op.
// ---------------------------------------------------------------------------
struct alignas(16) GeomRec {
    int base;
    int xoyo;          // xo | (yo<<16), in uint4 units
    unsigned int w01;  // h2 {-w00, -w01}
    unsigned int w23;  // h2 {-w10, -w11}
};

struct G4 {            // expanded form
    int t0, t1, t2, t3;
    h2_t w0s, w1s, w2s, w3s;  // splatted negated weights
};

__device__ __forceinline__ G4 expand(GeomRec g) {
    G4 o;
    int xo = g.xoyo & 0xffff;
    int yo = g.xoyo >> 16;
    o.t0 = g.base;
    o.t1 = g.base + xo;
    o.t2 = g.base + yo;
    o.t3 = g.base + yo + xo;
    h2_t w01 = __builtin_bit_cast(h2_t, g.w01);
    h2_t w23 = __builtin_bit_cast(h2_t, g.w23);
    o.w0s = h2_t{w01.x, w01.x};
    o.w1s = h2_t{w01.y, w01.y};
    o.w2s = h2_t{w23.x, w23.x};
    o.w3s = h2_t{w23.y, w23.y};
    return o;
}

// ---------------------------------------------------------------------------
// Main cost kernel v8.
// Phase 1: lane-parallel geometry -- 512 (pixel,nsub) pairs spread over 256
//          threads (2 each), GeomRec stored to LDS.
// Phase 2: 8-lane group = 1 pixel, 16 nsub per thread, depth-2 prefetch of
//          the 8 tap loads (next nsub issued before current combine).
// Packed-half2 bilinear+residual, dot2 square, DPP reduce, fused finalize.
// Grid: (H*W/32, NS/NSB, B), block 256.
// ---------------------------------------------------------------------------
__global__ __launch_bounds__(256, 4) void cost_kernel(
    const unsigned int* __restrict__ ftb, // (V, B, H*W, C) f16 features
    const float* __restrict__ depth,      // (B, H, W)
    const float* __restrict__ scale,      // (B, NS)
    const float* __restrict__ rt,         // (2, B, 12)
    float* __restrict__ cost,             // (B, NS) -- zeroed by transpose
    unsigned int* __restrict__ counter,   // completion counter -- zeroed
    float* __restrict__ outp,             // (B,) final output
    int total_blocks)
{
    const int tid  = threadIdx.x;
    const int lane = tid & 63;
    const int wv   = tid >> 6;
    const int nsg  = blockIdx.y;
    const int b    = blockIdx.z;

    __shared__ float s_lds[NSB];
    __shared__ float d_lds[32];
    __shared__ GeomRec geom[2][NSB][32];
    __shared__ float red[4][NSB];

    if (tid < NSB) s_lds[tid] = scale[b * NSC + nsg * NSB + tid];
    if (tid < 32)  d_lds[tid] = depth[b * NH * NW + blockIdx.x * 32 + tid];
    __syncthreads();

    // ---------------- phase 1: geometry (2 pairs per thread) ----------------
    {
        float R0[12], R1[12];
#pragma unroll
        for (int k = 0; k < 12; ++k) {
            R0[k] = rt[(0 * NB + b) * 12 + k];
            R1[k] = rt[(1 * NB + b) * 12 + k];
        }
        const float CXY = 64.0f / 63.5f;

#pragma unroll
        for (int pp = 0; pp < 2; ++pp) {
            int pr   = tid + pp * 256;      // 0..511
            int nsub = pr >> 5;             // 0..15
            int pix  = pr & 31;             // 0..31
            int gp   = blockIdx.x * 32 + pix;
            float fx = (float)(gp & (NW - 1));
            float fy = (float)(gp >> 7);
            float d  = d_lds[pix] * s_lds[nsub];

#pragma unroll
            for (int vi = 0; vi < 2; ++vi) {
                const float* R = vi ? R1 : R0;
                float px = (R[0] * fx + R[1] * fy + R[2]) * d + R[9];
                float py = (R[3] * fx + R[4] * fy + R[5]) * d + R[10];
                float pz = (R[6] * fx + R[7] * fy + R[8]) * d + R[11];
                float invz = __builtin_amdgcn_rcpf(pz);
                float ix = (px * invz) * CXY - 0.5f;
                float iy = (py * invz) * CXY - 0.5f;

                float x0f = floorf(ix), y0f = floorf(iy);
                float wx1 = ix - x0f, wx0 = 1.f - wx1;
                float wy1 = iy - y0f, wy0 = 1.f - wy1;

                float mx0 = (x0f >= 0.f  && x0f <= 127.f) ? wx0 : 0.f;
                float mx1 = (x0f >= -1.f && x0f <= 126.f) ? wx1 : 0.f;
                float my0 = (y0f >= 0.f  && y0f <= 127.f) ? wy0 : 0.f;
                float my1 = (y0f >= -1.f && y0f <= 126.f) ? wy1 : 0.f;

                int xi0 = (int)fminf(fmaxf(x0f, 0.f), 127.f);
                int yi0 = (int)fminf(fmaxf(y0f, 0.f), 127.f);
                int xo  = (x0f >= 0.f && x0f <= 126.f) ? 8 : 0;
                int yo  = (y0f >= 0.f && y0f <= 126.f) ? NW * 8 : 0;

                GeomRec g;
                g.base = (yi0 * NW + xi0) * 8;
                g.xoyo = xo | (yo << 16);
                g.w01  = __builtin_bit_cast(unsigned int, pack2(-(mx0 * my0), -(mx1 * my0)));
                g.w23  = __builtin_bit_cast(unsigned int, pack2(-(mx0 * my1), -(mx1 * my1)));
                geom[vi][nsub][pix] = g;
            }
        }
    }
    __syncthreads();

    // ---------------- phase 2: taps + combine, depth-2 prefetch -------------
    const int grp = lane >> 3;       // pixel group in wave (0..7)
    const int gl  = lane & 7;        // uint4 slot in the 128B record
    const int pix2 = wv * 8 + grp;   // block-local pixel (0..31)

    const uint4* f0q = (const uint4*)(ftb) +
        ((size_t)(0 * NB + b) * NH * NW + blockIdx.x * 32 + pix2) * 8 + gl;
    const uint4* v1q = (const uint4*)(ftb) + ((size_t)(1 * NB + b) * NH * NW) * 8 + gl;
    const uint4* v2q = (const uint4*)(ftb) + ((size_t)(2 * NB + b) * NH * NW) * 8 + gl;

    const uint4 f0u = *f0q;
    const h2_t* f0h = (const h2_t*)&f0u;

    G4 ea = expand(geom[0][0][pix2]);
    G4 eb = expand(geom[1][0][pix2]);
    uint4 a0 = v1q[ea.t0], a1 = v1q[ea.t1], a2 = v1q[ea.t2], a3 = v1q[ea.t3];
    uint4 b0 = v2q[eb.t0], b1 = v2q[eb.t1], b2 = v2q[eb.t2], b3 = v2q[eb.t3];

#pragma unroll
    for (int nsub = 0; nsub < NSB; ++nsub) {
        G4 na, nb;
        uint4 c0, c1, c2, c3, e0, e1, e2, e3;
        if (nsub + 1 < NSB) {
            na = expand(geom[0][nsub + 1][pix2]);
            nb = expand(geom[1][nsub + 1][pix2]);
            c0 = v1q[na.t0]; c1 = v1q[na.t1]; c2 = v1q[na.t2]; c3 = v1q[na.t3];
            e0 = v2q[nb.t0]; e1 = v2q[nb.t1]; e2 = v2q[nb.t2]; e3 = v2q[nb.t3];
        }

        const h2_t* pA0 = (const h2_t*)&a0;
        const h2_t* pA1 = (const h2_t*)&a1;
        const h2_t* pA2 = (const h2_t*)&a2;
        const h2_t* pA3 = (const h2_t*)&a3;
        const h2_t* pB0 = (const h2_t*)&b0;
        const h2_t* pB1 = (const h2_t*)&b1;
        const h2_t* pB2 = (const h2_t*)&b2;
        const h2_t* pB3 = (const h2_t*)&b3;

        h2_t r[4];
        float sq1 = 0.f, sq2 = 0.f;
#pragma unroll
        for (int j = 0; j < 4; ++j) {
            h2_t rr = f0h[j];
            rr += pA0[j] * ea.w0s;
            rr += pA1[j] * ea.w1s;
            rr += pA2[j] * ea.w2s;
            rr += pA3[j] * ea.w3s;
            r[j] = rr;
            sq1 = dot2acc(rr, sq1);
        }
#pragma unroll
        for (int j = 0; j < 4; ++j) {
            h2_t rr = r[j];
            rr += pB0[j] * eb.w0s;
            rr += pB1[j] * eb.w1s;
            rr += pB2[j] * eb.w2s;
            rr += pB3[j] * eb.w3s;
            sq2 = dot2acc(rr, sq2);
        }

        // 8-lane group reduce (row_shr prefix; tails at lanes 7,15,...)
        sq1 = dpp_add<0x111>(sq1);
        sq1 = dpp_add<0x112>(sq1);
        sq1 = dpp_add<0x114>(sq1);
        sq2 = dpp_add<0x111>(sq2);
        sq2 = dpp_add<0x112>(sq2);
        sq2 = dpp_add<0x114>(sq2);
        float sv = sqrtf(sq1) + sqrtf(sq2);
        sv = dpp_add<0x118>(sv);   // row_shr:8
        sv = dpp_add<0x142>(sv);   // row_bcast:15
        sv = dpp_add<0x143>(sv);   // row_bcast:31 -> wave total in lane 63
        if (lane == 63) red[wv][nsub] = sv;

        // rotate prefetch buffers (full unroll -> register renaming)
        ea = na; eb = nb;
        a0 = c0; a1 = c1; a2 = c2; a3 = c3;
        b0 = e0; b1 = e1; b2 = e2; b3 = e3;
    }

    __syncthreads();
    if (tid < NSB) {
        float t = red[0][tid] + red[1][tid] + red[2][tid] + red[3][tid];
        atomicAdd(&cost[b * NSC + nsg * NSB + tid], t * (0.5f / (float)(NH * NW)));
        __threadfence();
    }
    __syncthreads();

    // ---- completion counter; last block runs the finalize ----
    __shared__ unsigned int lastflag;
    if (tid == 0) {
        unsigned int prev = atomicAdd(counter, 1u);
        lastflag = (prev == (unsigned int)(total_blocks - 1)) ? 1u : 0u;
    }
    __syncthreads();
    if (lastflag && tid < NB * NSC) {
        __threadfence();
        int bb = tid >> 5;
        int ns = tid & 31;
        float c  = atomicAdd(&cost[bb * NSC + ns], 0.0f);  // coherent read
        float sv = scale[bb * NSC + ns];

        float m = c;
#pragma unroll
        for (int mk = 1; mk < 32; mk <<= 1) m = fmaxf(m, __shfl_xor(m, mk, 64));
        float e = __expf(c - m);
        float sum = e;
#pragma unroll
        for (int mk = 1; mk < 32; mk <<= 1) sum += __shfl_xor(sum, mk, 64);
        float val = (e / sum) * sv;
#pragma unroll
        for (int mk = 1; mk < 32; mk <<= 1) val += __shfl_xor(val, mk, 64);
        if (ns == 0) outp[bb] = val;
    }
}

// ---------------------------------------------------------------------------
extern "C" void kernel_launch(void* const* d_in, const int* in_sizes, int n_in,
                              void* d_out, int out_size, void* d_ws, size_t ws_size,
                              hipStream_t stream) {
    const float* features   = (const float*)d_in[0];  // (V,B,C,H,W)
    const float* intrinsics = (const float*)d_in[1];  // (V,B,3,3)
    const float* cam2world  = (const float*)d_in[2];  // (V,B,4,4)
    const float* scale_hypo = (const float*)d_in[3];  // (B,NS)
    const float* depth_init = (const float*)d_in[4];  // (B,H,W)
    float* out = (float*)d_out;                       // (B,)

    // workspace layout
    unsigned int* ftb = (unsigned int*)d_ws;                      // V*B*H*W*C/2 uints (f16 pairs)
    float* rt   = (float*)(ftb + (size_t)NV * NB * NH * NW * (NC / 2));
    float* cost = rt + 2 * NB * 12;                               // B*NS floats
    unsigned int* counter = (unsigned int*)(cost + NB * NSC);

    dim3 tgrid(NH, NV * NB);
    transpose_kernel<<<tgrid, 256, 0, stream>>>(features, ftb, intrinsics, cam2world,
                                                rt, cost, counter);

    dim3 cgrid(NH * NW / 32, NSC / NSB, NB);
    int total_blocks = cgrid.x * cgrid.y * cgrid.z;
    cost_kernel<<<cgrid, 256, 0, stream>>>(ftb, depth_init, scale_hypo, rt,
                                           cost, counter, out, total_blocks);
}